// Round 2
// baseline (9650.418 us; speedup 1.0000x reference)
//
#include <hip/hip_runtime.h>
#include <hip/hip_bf16.h>

#define NN 50000    // nodes
#define NE 100000   // edges
#define NG 2048     // graphs
#define NF 14
#define D 64
#define EB 64       // edges per block in fused path

__device__ __forceinline__ float sigmoidf(float x) { return 1.f / (1.f + expf(-x)); }

// ---------------- utility ----------------
__global__ void zero_kernel(float* p, int n) {
    int i = blockIdx.x * 256 + threadIdx.x;
    if (i < n) p[i] = 0.f;
}

// dst[c*rows + r] = src[r*cols + c]
__global__ void transpose_kernel(const float* __restrict__ src, float* __restrict__ dst,
                                 int rows, int cols) {
    int idx = blockIdx.x * 256 + threadIdx.x;
    if (idx < rows * cols) {
        int r = idx / cols, c = idx - r * cols;
        dst[c * rows + r] = src[idx];
    }
}

// ---------------- lin0: out = relu(x @ lin0_w.T + b) ----------------
__global__ void lin0_kernel(const float* __restrict__ x, const float* __restrict__ w,
                            const float* __restrict__ b, float* __restrict__ out) {
    int grp = threadIdx.x >> 6;
    int d = threadIdx.x & 63;
    int n = blockIdx.x * 4 + grp;
    __shared__ float xs[4][NF];
    int t = threadIdx.x;
    if (t < 4 * NF) {
        int r = t / NF, c = t - r * NF;
        int nn2 = blockIdx.x * 4 + r;
        xs[r][c] = (nn2 < NN) ? x[nn2 * NF + c] : 0.f;
    }
    __syncthreads();
    if (n >= NN) return;
    float acc = b[d];
#pragma unroll
    for (int k = 0; k < NF; k++) acc += xs[grp][k] * w[d * NF + k];
    out[n * D + d] = fmaxf(acc, 0.f);
}

// ================= BIG-WS PATH (materialized bf16 ew) =================

// edge nn layer 1: hidden = relu(ea @ w1.T + b1)  [f32]
__global__ void edge_nn1_kernel(const float* __restrict__ ea, const float* __restrict__ w1,
                                const float* __restrict__ b1, float* __restrict__ hidden) {
    int grp = threadIdx.x >> 7;
    int k = threadIdx.x & 127;
    int e = blockIdx.x * 2 + grp;
    __shared__ float es[2][4];
    int t = threadIdx.x;
    if (t < 8) {
        int r = t >> 2, c = t & 3;
        int ee = blockIdx.x * 2 + r;
        es[r][c] = (ee < NE) ? ea[ee * 4 + c] : 0.f;
    }
    __syncthreads();
    if (e >= NE) return;
    float acc = b1[k];
#pragma unroll
    for (int j = 0; j < 4; j++) acc += es[grp][j] * w1[k * 4 + j];
    hidden[(size_t)e * 128 + k] = fmaxf(acc, 0.f);
}

// ew GEMM: ew[e, c] = hidden[e,:] @ w2[c,:] + b2[c], bf16 out
__global__ __launch_bounds__(256) void ew_gemm_kernel(const float* __restrict__ hidden,
                                                      const float* __restrict__ w2,
                                                      const float* __restrict__ b2,
                                                      __hip_bfloat16* __restrict__ ew) {
    __shared__ __align__(16) float At[64][68];  // At[k][row]
    __shared__ __align__(16) float Bt[64][68];  // Bt[k][col]
    int tid = threadIdx.x;
    int m0 = blockIdx.x * 64;
    int c0 = blockIdx.y * 64;
    int tx = tid & 15, ty = tid >> 4;
    int rr = ty * 4, cc = tx * 4;
    float acc[4][4] = {};
    for (int kh = 0; kh < 2; kh++) {
        __syncthreads();
#pragma unroll
        for (int it = 0; it < 4; it++) {
            int flat = (tid + it * 256) * 4;
            int r = flat >> 6, kk = flat & 63;
            int row = m0 + r;
            float4 va = make_float4(0.f, 0.f, 0.f, 0.f);
            if (row < NE) va = *(const float4*)(hidden + (size_t)row * 128 + kh * 64 + kk);
            At[kk + 0][r] = va.x; At[kk + 1][r] = va.y; At[kk + 2][r] = va.z; At[kk + 3][r] = va.w;
            float4 vb = *(const float4*)(w2 + (size_t)(c0 + r) * 128 + kh * 64 + kk);
            Bt[kk + 0][r] = vb.x; Bt[kk + 1][r] = vb.y; Bt[kk + 2][r] = vb.z; Bt[kk + 3][r] = vb.w;
        }
        __syncthreads();
#pragma unroll 8
        for (int kk = 0; kk < 64; kk++) {
            float4 a = *(const float4*)&At[kk][rr];
            float4 b = *(const float4*)&Bt[kk][cc];
            float av[4] = {a.x, a.y, a.z, a.w};
            float bv[4] = {b.x, b.y, b.z, b.w};
#pragma unroll
            for (int i = 0; i < 4; i++)
#pragma unroll
                for (int j = 0; j < 4; j++) acc[i][j] = fmaf(av[i], bv[j], acc[i][j]);
        }
    }
#pragma unroll
    for (int i = 0; i < 4; i++) {
        int row = m0 + rr + i;
        if (row >= NE) break;
        union { __hip_bfloat16 h4[4]; uint2 u; } pk;
#pragma unroll
        for (int j = 0; j < 4; j++) pk.h4[j] = __float2bfloat16(acc[i][j] + b2[c0 + cc + j]);
        *(uint2*)((char*)ew + ((size_t)row * 4096 + c0 + cc) * 2) = pk.u;
    }
}

// message + scatter: agg[dst] += out[src] @ ew[e]
__global__ void msg_kernel(const float* __restrict__ out, const __hip_bfloat16* __restrict__ ew,
                           const int* __restrict__ ei, float* __restrict__ agg) {
    int e = blockIdx.x;
    int o = threadIdx.x;  // 64
    int src = ei[e], dst = ei[NE + e];
    __shared__ float s[64];
    s[o] = out[src * D + o];
    __syncthreads();
    const __hip_bfloat16* row = ew + (size_t)e * 4096;
    float acc = 0.f;
#pragma unroll 16
    for (int i = 0; i < 64; i++) acc += s[i] * __bfloat162float(row[i * 64 + o]);
    atomicAdd(&agg[dst * D + o], acc);
}

// ================= SMALL-WS PATH (fused bilinear message) =================
// agg[dst_e, o] += sum_{i,k} h[src_e,i] * relu(ea_e@W1^T+b1)[k] * W2[i*64+o, k]  (+ b2 term)
__global__ __launch_bounds__(256) void fused_msg_kernel(
    const float* __restrict__ h, const float* __restrict__ ea,
    const float* __restrict__ w1, const float* __restrict__ b1,
    const float* __restrict__ w2, const float* __restrict__ b2,
    const int* __restrict__ ei, float* __restrict__ agg) {
    __shared__ float hidF[EB][132];   // hidden[e][k], padded
    __shared__ float hsF[EB][68];     // h[src_e][i], padded
    __shared__ float W2s[64][132];    // W2 slice for current i: [o][k]
    __shared__ float seaS[EB][4];
    __shared__ float w1S[128][4];
    __shared__ float b1S[128];
    __shared__ int sidx[EB], didx[EB];
    int tid = threadIdx.x;
    int e0 = blockIdx.x * EB;

    if (tid < EB) {
        int e = e0 + tid;
        sidx[tid] = (e < NE) ? ei[e] : 0;
        didx[tid] = (e < NE) ? ei[NE + e] : 0;
    }
    {
        int e = tid >> 2, j = tid & 3;   // 256 threads cover 64x4
        int ge = e0 + e;
        seaS[e][j] = (ge < NE) ? ea[ge * 4 + j] : 0.f;
    }
    if (tid < 128) {
        w1S[tid][0] = w1[tid * 4 + 0]; w1S[tid][1] = w1[tid * 4 + 1];
        w1S[tid][2] = w1[tid * 4 + 2]; w1S[tid][3] = w1[tid * 4 + 3];
        b1S[tid] = b1[tid];
    }
    __syncthreads();
    // hidden tile in-LDS: hidF[e][k] = relu(b1[k] + ea[e,:]@w1[k,:])
    for (int idx = tid; idx < EB * 128; idx += 256) {
        int e = idx >> 7, k = idx & 127;
        float v = b1S[k] + seaS[e][0] * w1S[k][0] + seaS[e][1] * w1S[k][1] +
                  seaS[e][2] * w1S[k][2] + seaS[e][3] * w1S[k][3];
        hidF[e][k] = fmaxf(v, 0.f);
    }
    // gather h[src] tile
    {
        int e = tid >> 2, i0 = (tid & 3) * 16;
        bool valid = (e0 + e) < NE;
        const float4* hp = (const float4*)(h + (size_t)sidx[e] * 64 + i0);
        float4* dp = (float4*)&hsF[e][i0];
#pragma unroll
        for (int u = 0; u < 4; u++) dp[u] = valid ? hp[u] : make_float4(0.f, 0.f, 0.f, 0.f);
    }
    // prefetch W2 slice i=0 into registers (slice i is contiguous: rows i*64..i*64+63)
    float4 pre[8];
    {
        const float4* s4 = (const float4*)w2;
#pragma unroll
        for (int u = 0; u < 8; u++) pre[u] = s4[tid + u * 256];
    }
    int eg = tid & 15, og = tid >> 4;  // edges eg+16j, outputs og+16m
    float acc[4][4] = {};
    for (int i = 0; i < 64; i++) {
        __syncthreads();  // prev readers of W2s done (and staging done at i=0)
#pragma unroll
        for (int u = 0; u < 8; u++) {
            int flat = (tid + u * 256) * 4;
            int o = flat >> 7, k = flat & 127;
            *(float4*)&W2s[o][k] = pre[u];
        }
        if (i < 63) {
            const float4* s4 = (const float4*)(w2 + (size_t)(i + 1) * 8192);
#pragma unroll
            for (int u = 0; u < 8; u++) pre[u] = s4[tid + u * 256];
        }
        __syncthreads();
        float a0 = hsF[eg][i], a1 = hsF[eg + 16][i], a2 = hsF[eg + 32][i], a3 = hsF[eg + 48][i];
        float t[4][4] = {};
#pragma unroll 2
        for (int k = 0; k < 128; k += 4) {
            float4 w0 = *(const float4*)&W2s[og][k];
            float4 w1v = *(const float4*)&W2s[og + 16][k];
            float4 w2v = *(const float4*)&W2s[og + 32][k];
            float4 w3v = *(const float4*)&W2s[og + 48][k];
#pragma unroll
            for (int j = 0; j < 4; j++) {
                float4 hv = *(const float4*)&hidF[eg + 16 * j][k];
                t[j][0] += hv.x * w0.x + hv.y * w0.y + hv.z * w0.z + hv.w * w0.w;
                t[j][1] += hv.x * w1v.x + hv.y * w1v.y + hv.z * w1v.z + hv.w * w1v.w;
                t[j][2] += hv.x * w2v.x + hv.y * w2v.y + hv.z * w2v.z + hv.w * w2v.w;
                t[j][3] += hv.x * w3v.x + hv.y * w3v.y + hv.z * w3v.z + hv.w * w3v.w;
            }
        }
#pragma unroll
        for (int m = 0; m < 4; m++) {
            acc[0][m] += a0 * t[0][m];
            acc[1][m] += a1 * t[1][m];
            acc[2][m] += a2 * t[2][m];
            acc[3][m] += a3 * t[3][m];
        }
    }
    // b2 term: acc[j][m] += sum_i hs[e_j][i] * b2[i*64 + o_m]
    for (int i = 0; i < 64; i++) {
        float b0 = b2[i * 64 + og], b1v = b2[i * 64 + og + 16];
        float b2v = b2[i * 64 + og + 32], b3v = b2[i * 64 + og + 48];
        float a0 = hsF[eg][i], a1 = hsF[eg + 16][i], a2 = hsF[eg + 32][i], a3 = hsF[eg + 48][i];
        acc[0][0] += a0 * b0; acc[0][1] += a0 * b1v; acc[0][2] += a0 * b2v; acc[0][3] += a0 * b3v;
        acc[1][0] += a1 * b0; acc[1][1] += a1 * b1v; acc[1][2] += a1 * b2v; acc[1][3] += a1 * b3v;
        acc[2][0] += a2 * b0; acc[2][1] += a2 * b1v; acc[2][2] += a2 * b2v; acc[2][3] += a2 * b3v;
        acc[3][0] += a3 * b0; acc[3][1] += a3 * b1v; acc[3][2] += a3 * b2v; acc[3][3] += a3 * b3v;
    }
#pragma unroll
    for (int j = 0; j < 4; j++) {
        int e = eg + 16 * j;
        if (e0 + e < NE) {
            int dn = didx[e];
            atomicAdd(&agg[(size_t)dn * 64 + og], acc[j][0]);
            atomicAdd(&agg[(size_t)dn * 64 + og + 16], acc[j][1]);
            atomicAdd(&agg[(size_t)dn * 64 + og + 32], acc[j][2]);
            atomicAdd(&agg[(size_t)dn * 64 + og + 48], acc[j][3]);
        }
    }
}

// ---------------- degree ----------------
__global__ void deg_kernel(const int* __restrict__ ei, float* __restrict__ deg) {
    int e = blockIdx.x * 256 + threadIdx.x;
    if (e < NE) atomicAdd(&deg[ei[NE + e]], 1.0f);
}
__global__ void invdeg_kernel(float* deg) {
    int n = blockIdx.x * 256 + threadIdx.x;
    if (n < NN) deg[n] = 1.0f / fmaxf(deg[n], 1.0f);
}

// ---------------- conv (in-place into agg): agg = relu(out @ conv_root + agg*invdeg + bias) ----------------
__global__ void conv_kernel(const float* __restrict__ out, float* __restrict__ agg,
                            const float* __restrict__ invdeg, const float* __restrict__ root,
                            const float* __restrict__ cbias) {
    int grp = threadIdx.x >> 6;
    int d = threadIdx.x & 63;
    int n = blockIdx.x * 4 + grp;
    __shared__ float s[4][64];
    if (n < NN) s[grp][d] = out[n * D + d];
    __syncthreads();
    if (n >= NN) return;
    float acc = 0.f;
    const float* sr = s[grp];
#pragma unroll 8
    for (int k = 0; k < 64; k++) acc += sr[k] * root[k * D + d];
    agg[n * D + d] = fmaxf(acc + agg[n * D + d] * invdeg[n] + cbias[d], 0.f);
}

// ---------------- GRU: h = GRUCell(m, h); weights pre-transposed [64][192] ----------------
__global__ __launch_bounds__(256) void gru_kernel(const float* __restrict__ m, float* __restrict__ h,
                                                  const float* __restrict__ wihT,
                                                  const float* __restrict__ whhT,
                                                  const float* __restrict__ bih,
                                                  const float* __restrict__ bhh) {
    int tid = threadIdx.x;
    int grp = tid >> 6;
    int j = tid & 63;
    int n0 = blockIdx.x * 16;
    int nd0 = grp * 4;
    __shared__ float ms[16][64];
    __shared__ float hs[16][64];
    for (int i = tid; i < 16 * 64; i += 256) {
        int nd = i >> 6, dd = i & 63;
        ms[nd][dd] = m[(n0 + nd) * D + dd];
        hs[nd][dd] = h[(n0 + nd) * D + dd];
    }
    __syncthreads();
    float air[4] = {}, aiz[4] = {}, ain[4] = {};
    float ahr[4] = {}, ahz[4] = {}, ahn[4] = {};
#pragma unroll 4
    for (int k = 0; k < 64; k++) {
        float wr = wihT[k * 192 + j];
        float wz = wihT[k * 192 + 64 + j];
        float wn = wihT[k * 192 + 128 + j];
        float vr = whhT[k * 192 + j];
        float vz = whhT[k * 192 + 64 + j];
        float vn = whhT[k * 192 + 128 + j];
#pragma unroll
        for (int q = 0; q < 4; q++) {
            float mv = ms[nd0 + q][k], hv = hs[nd0 + q][k];
            air[q] = fmaf(mv, wr, air[q]);
            aiz[q] = fmaf(mv, wz, aiz[q]);
            ain[q] = fmaf(mv, wn, ain[q]);
            ahr[q] = fmaf(hv, vr, ahr[q]);
            ahz[q] = fmaf(hv, vz, ahz[q]);
            ahn[q] = fmaf(hv, vn, ahn[q]);
        }
    }
    float br = bih[j], bz = bih[64 + j], bn = bih[128 + j];
    float cr = bhh[j], cz = bhh[64 + j], cn = bhh[128 + j];
#pragma unroll
    for (int q = 0; q < 4; q++) {
        float r = sigmoidf(air[q] + br + ahr[q] + cr);
        float z = sigmoidf(aiz[q] + bz + ahz[q] + cz);
        float nn2 = tanhf(ain[q] + bn + r * (ahn[q] + cn));
        float hv = hs[nd0 + q][j];
        h[(n0 + nd0 + q) * D + j] = (1.f - z) * nn2 + z * hv;
    }
}

// ---------------- graph starts (batch sorted) ----------------
__global__ void starts_kernel(const int* __restrict__ batch, int* __restrict__ start) {
    int n = blockIdx.x * 256 + threadIdx.x;
    if (n >= NN) return;
    int b = batch[n];
    int bp = (n == 0) ? -1 : batch[n - 1];
    for (int g = bp + 1; g <= b; g++) start[g] = n;
    if (n == NN - 1) {
        for (int g = b + 1; g <= NG; g++) start[g] = NN;
    }
}

// ---------------- Set2Set LSTM step ----------------
__global__ void s2s_lstm_kernel(const float* __restrict__ qstar, float* __restrict__ hh,
                                float* __restrict__ cc, const float* __restrict__ wihT,
                                const float* __restrict__ whhT, const float* __restrict__ bih,
                                const float* __restrict__ bhh) {
    int g = blockIdx.x;
    int j = threadIdx.x;  // 256
    __shared__ float q[128], hsh[64], gates[256];
    if (j < 128) q[j] = qstar[g * 128 + j];
    if (j < 64) hsh[j] = hh[g * 64 + j];
    __syncthreads();
    float acc = bih[j] + bhh[j];
#pragma unroll 8
    for (int k = 0; k < 128; k++) acc = fmaf(q[k], wihT[k * 256 + j], acc);
#pragma unroll 8
    for (int k = 0; k < 64; k++) acc = fmaf(hsh[k], whhT[k * 256 + j], acc);
    gates[j] = acc;
    __syncthreads();
    if (j < 64) {
        float gi = gates[j], gf = gates[64 + j], gg = gates[128 + j], go = gates[192 + j];
        float c2 = sigmoidf(gf) * cc[g * 64 + j] + sigmoidf(gi) * tanhf(gg);
        float h2 = sigmoidf(go) * tanhf(c2);
        cc[g * 64 + j] = c2;
        hh[g * 64 + j] = h2;
    }
}

// ---------------- Set2Set attention + pooling; writes q_star ----------------
__global__ void s2s_attn_kernel(const float* __restrict__ out, const float* __restrict__ hh,
                                const int* __restrict__ start, float* __restrict__ qstar) {
    int g = blockIdx.x;
    int d = threadIdx.x;  // 64
    int n0 = start[g], n1 = start[g + 1];
    float hd = hh[g * 64 + d];
    float mx = -INFINITY;
    for (int n = n0; n < n1; n++) {
        float p = out[n * D + d] * hd;
#pragma unroll
        for (int off = 32; off; off >>= 1) p += __shfl_xor(p, off);
        mx = fmaxf(mx, p);
    }
    float sexp = 0.f, racc = 0.f;
    for (int n = n0; n < n1; n++) {
        float ond = out[n * D + d];
        float p = ond * hd;
#pragma unroll
        for (int off = 32; off; off >>= 1) p += __shfl_xor(p, off);
        float a = expf(p - mx);
        sexp += a;
        racc = fmaf(a, ond, racc);
    }
    float r = racc / (sexp + 1e-16f);
    qstar[g * 128 + d] = hd;
    qstar[g * 128 + 64 + d] = r;
}

// ---------------- head ----------------
__global__ void final_kernel(const float* __restrict__ qstar, const float* __restrict__ w1,
                             const float* __restrict__ b1, const float* __restrict__ w2,
                             const float* __restrict__ b2, float* __restrict__ y) {
    int g = blockIdx.x;
    int d = threadIdx.x;  // 64
    __shared__ float q[128];
    q[d] = qstar[g * 128 + d];
    q[64 + d] = qstar[g * 128 + 64 + d];
    __syncthreads();
    float acc = b1[d];
#pragma unroll 8
    for (int k = 0; k < 128; k++) acc = fmaf(q[k], w1[d * 128 + k], acc);
    acc = fmaxf(acc, 0.f);
    float p = acc * w2[d];
#pragma unroll
    for (int off = 32; off; off >>= 1) p += __shfl_xor(p, off);
    if (d == 0) y[g] = p + b2[0];
}

extern "C" void kernel_launch(void* const* d_in, const int* in_sizes, int n_in,
                              void* d_out, int out_size, void* d_ws, size_t ws_size,
                              hipStream_t stream) {
    (void)in_sizes; (void)n_in; (void)out_size;
    const float* x = (const float*)d_in[0];
    const int* edge_index = (const int*)d_in[1];
    const float* edge_attr = (const float*)d_in[2];
    const int* batch = (const int*)d_in[3];
    const float* lin0_w = (const float*)d_in[4];
    const float* lin0_b = (const float*)d_in[5];
    const float* nn_w1 = (const float*)d_in[6];
    const float* nn_b1 = (const float*)d_in[7];
    const float* nn_w2 = (const float*)d_in[8];
    const float* nn_b2 = (const float*)d_in[9];
    const float* conv_root = (const float*)d_in[10];
    const float* conv_bias = (const float*)d_in[11];
    const float* gru_w_ih = (const float*)d_in[12];
    const float* gru_w_hh = (const float*)d_in[13];
    const float* gru_b_ih = (const float*)d_in[14];
    const float* gru_b_hh = (const float*)d_in[15];
    const float* s2s_w_ih = (const float*)d_in[16];
    const float* s2s_w_hh = (const float*)d_in[17];
    const float* s2s_b_ih = (const float*)d_in[18];
    const float* s2s_b_hh = (const float*)d_in[19];
    const float* lin1_w = (const float*)d_in[20];
    const float* lin1_b = (const float*)d_in[21];
    const float* lin2_w = (const float*)d_in[22];
    const float* lin2_b = (const float*)d_in[23];
    float* y = (float*)d_out;

    char* ws = (char*)d_ws;
    size_t off = 0;
    auto alloc = [&](size_t bytes) {
        void* p = ws + off;
        off = (off + bytes + 255) & ~(size_t)255;
        return p;
    };
    // common (small-footprint) allocations
    float* h = (float*)alloc((size_t)NN * D * 4);
    float* agg = (float*)alloc((size_t)NN * D * 4);
    float* invdeg = (float*)alloc((size_t)NN * 4);
    int* start = (int*)alloc((size_t)(NG + 1) * 4);
    float* qstar = (float*)alloc((size_t)NG * 128 * 4);
    float* hh = (float*)alloc((size_t)NG * 64 * 4);
    float* ccv = (float*)alloc((size_t)NG * 64 * 4);
    float* gruT_ih = (float*)alloc(192 * 64 * 4);
    float* gruT_hh = (float*)alloc(192 * 64 * 4);
    float* s2sT_ih = (float*)alloc(256 * 128 * 4);
    float* s2sT_hh = (float*)alloc(256 * 64 * 4);

    // big path needs hidden f32 (51.2 MB) + ew bf16 (819.2 MB) on top of common
    size_t hidden_bytes = (size_t)NE * 128 * 4;
    size_t ew_bytes = (size_t)NE * 4096 * 2;
    size_t big_need = off + ((hidden_bytes + 255) & ~(size_t)255) + ((ew_bytes + 255) & ~(size_t)255);
    bool big = (big_need <= ws_size);
    float* hidden = nullptr;
    __hip_bfloat16* ew = nullptr;
    if (big) {
        hidden = (float*)alloc(hidden_bytes);
        ew = (__hip_bfloat16*)alloc(ew_bytes);
    }

    // prep
    zero_kernel<<<(NN + 255) / 256, 256, 0, stream>>>(invdeg, NN);
    transpose_kernel<<<(192 * 64 + 255) / 256, 256, 0, stream>>>(gru_w_ih, gruT_ih, 192, 64);
    transpose_kernel<<<(192 * 64 + 255) / 256, 256, 0, stream>>>(gru_w_hh, gruT_hh, 192, 64);
    transpose_kernel<<<(256 * 128 + 255) / 256, 256, 0, stream>>>(s2s_w_ih, s2sT_ih, 256, 128);
    transpose_kernel<<<(256 * 64 + 255) / 256, 256, 0, stream>>>(s2s_w_hh, s2sT_hh, 256, 64);
    lin0_kernel<<<NN / 4, 256, 0, stream>>>(x, lin0_w, lin0_b, h);
    deg_kernel<<<(NE + 255) / 256, 256, 0, stream>>>(edge_index, invdeg);
    invdeg_kernel<<<(NN + 255) / 256, 256, 0, stream>>>(invdeg);
    starts_kernel<<<(NN + 255) / 256, 256, 0, stream>>>(batch, start);
    if (big) {
        edge_nn1_kernel<<<NE / 2, 256, 0, stream>>>(edge_attr, nn_w1, nn_b1, hidden);
        dim3 g3((NE + 63) / 64, 4096 / 64);
        ew_gemm_kernel<<<g3, 256, 0, stream>>>(hidden, nn_w2, nn_b2, ew);
    }

    // 3 message-passing + GRU iterations
    for (int it = 0; it < 3; it++) {
        zero_kernel<<<(NN * D + 255) / 256, 256, 0, stream>>>(agg, NN * D);
        if (big) {
            msg_kernel<<<NE, 64, 0, stream>>>(h, ew, edge_index, agg);
        } else {
            fused_msg_kernel<<<(NE + EB - 1) / EB, 256, 0, stream>>>(
                h, edge_attr, nn_w1, nn_b1, nn_w2, nn_b2, edge_index, agg);
        }
        conv_kernel<<<NN / 4, 256, 0, stream>>>(h, agg, invdeg, conv_root, conv_bias);
        gru_kernel<<<NN / 16, 256, 0, stream>>>(agg, h, gruT_ih, gruT_hh, gru_b_ih, gru_b_hh);
    }

    // Set2Set
    zero_kernel<<<(NG * 128 + 255) / 256, 256, 0, stream>>>(qstar, NG * 128);
    zero_kernel<<<(NG * 64 + 255) / 256, 256, 0, stream>>>(hh, NG * 64);
    zero_kernel<<<(NG * 64 + 255) / 256, 256, 0, stream>>>(ccv, NG * 64);
    for (int t = 0; t < 3; t++) {
        s2s_lstm_kernel<<<NG, 256, 0, stream>>>(qstar, hh, ccv, s2sT_ih, s2sT_hh, s2s_b_ih, s2s_b_hh);
        s2s_attn_kernel<<<NG, 64, 0, stream>>>(h, hh, start, qstar);
    }
    final_kernel<<<NG, 64, 0, stream>>>(qstar, lin1_w, lin1_b, lin2_w, lin2_b, y);
}

// Round 3
// 1324.220 us; speedup vs baseline: 7.2876x; 7.2876x over previous
//
#include <hip/hip_runtime.h>
#include <hip/hip_bf16.h>

#define NN 50000    // nodes
#define NE 100000   // edges
#define NG 2048     // graphs
#define NF 14
#define D 64
#define EB 64       // edges per block in msg kernel

typedef __attribute__((ext_vector_type(8))) short bf16x8;
typedef __attribute__((ext_vector_type(4))) float f32x4;

__device__ __forceinline__ float sigmoidf(float x) { return 1.f / (1.f + expf(-x)); }

// ---------------- utility ----------------
__global__ void zero_kernel(float* p, int n) {
    int i = blockIdx.x * 256 + threadIdx.x;
    if (i < n) p[i] = 0.f;
}

__global__ void cvt_bf16_kernel(const float* __restrict__ src, __hip_bfloat16* __restrict__ dst, int n) {
    int i = blockIdx.x * 256 + threadIdx.x;
    if (i < n) dst[i] = __float2bfloat16(src[i]);
}

// dst[c*rows + r] = src[r*cols + c]
__global__ void transpose_kernel(const float* __restrict__ src, float* __restrict__ dst,
                                 int rows, int cols) {
    int idx = blockIdx.x * 256 + threadIdx.x;
    if (idx < rows * cols) {
        int r = idx / cols, c = idx - r * cols;
        dst[c * rows + r] = src[idx];
    }
}

// ---------------- lin0: out = relu(x @ lin0_w.T + b) ----------------
__global__ void lin0_kernel(const float* __restrict__ x, const float* __restrict__ w,
                            const float* __restrict__ b, float* __restrict__ out) {
    int grp = threadIdx.x >> 6;
    int d = threadIdx.x & 63;
    int n = blockIdx.x * 4 + grp;
    __shared__ float xs[4][NF];
    int t = threadIdx.x;
    if (t < 4 * NF) {
        int r = t / NF, c = t - r * NF;
        int nn2 = blockIdx.x * 4 + r;
        xs[r][c] = (nn2 < NN) ? x[nn2 * NF + c] : 0.f;
    }
    __syncthreads();
    if (n >= NN) return;
    float acc = b[d];
#pragma unroll
    for (int k = 0; k < NF; k++) acc += xs[grp][k] * w[d * NF + k];
    out[n * D + d] = fmaxf(acc, 0.f);
}

// ================= MFMA fused message kernel =================
// agg[dst_e, o] += sum_i h[src_e, i] * ( hidden[e,:] . W2[i*64+o, :] )  + sum_i h[src_e,i]*b2[i*64+o]
// Per block: 64 edges, full 64 outputs. Per i: S_i = hidden_tile(bf16) @ W2r_i(bf16) via MFMA,
// then acc += h[e,i] * S_i (fixup on C-layout regs). A-fragments are i-invariant (preloaded).
__global__ __launch_bounds__(256) void msg_mfma_kernel(
    const float* __restrict__ h, const float* __restrict__ ea,
    const float* __restrict__ w1, const float* __restrict__ b1,
    const __hip_bfloat16* __restrict__ w2r,  // bf16 copy of nn_w2, flat [i][o][k] == row order of nn_w2
    const float* __restrict__ b2, const int* __restrict__ ei,
    float* __restrict__ agg)
{
    __shared__ __hip_bfloat16 hid[EB][136];    // hidden[e][k] bf16, stride 136 (pad 8)
    __shared__ __hip_bfloat16 hsrc[EB][72];    // h[src_e][i] bf16, stride 72
    __shared__ __hip_bfloat16 Bs[2][64][136];  // W2r slice [o][k] double-buffered
    __shared__ __hip_bfloat16 B2s[64][72];     // b2 reshaped [o][i]
    __shared__ float w1s[128][4];
    __shared__ float b1s[128];
    __shared__ float eas[EB][4];
    __shared__ int didx[EB];

    int tid = threadIdx.x;
    int e0 = blockIdx.x * EB;

    // --- stage ea, w1, b1, didx ---
    {
        int e = tid >> 2, j = tid & 3;
        int ge = e0 + e;
        eas[e][j] = (ge < NE) ? ea[ge * 4 + j] : 0.f;
    }
    if (tid < 128) {
        w1s[tid][0] = w1[tid * 4 + 0]; w1s[tid][1] = w1[tid * 4 + 1];
        w1s[tid][2] = w1[tid * 4 + 2]; w1s[tid][3] = w1[tid * 4 + 3];
        b1s[tid] = b1[tid];
    }
    if (tid < EB) didx[tid] = (e0 + tid < NE) ? ei[NE + e0 + tid] : -1;
    // --- gather h[src] -> hsrc bf16 ---
    {
        int e = tid >> 2, i0 = (tid & 3) * 16;
        int ge = e0 + e;
        if (ge < NE) {
            int src = ei[ge];
            const float4* hp = (const float4*)(h + (size_t)src * 64 + i0);
#pragma unroll
            for (int u = 0; u < 4; u++) {
                float4 v = hp[u];
                hsrc[e][i0 + u * 4 + 0] = __float2bfloat16(v.x);
                hsrc[e][i0 + u * 4 + 1] = __float2bfloat16(v.y);
                hsrc[e][i0 + u * 4 + 2] = __float2bfloat16(v.z);
                hsrc[e][i0 + u * 4 + 3] = __float2bfloat16(v.w);
            }
        } else {
#pragma unroll
            for (int u = 0; u < 16; u++) hsrc[e][i0 + u] = __float2bfloat16(0.f);
        }
    }
    // --- preload B slice i=0 ---
    {
        int row = tid >> 2, seg = (tid & 3) * 32;
        const bf16x8* gp = (const bf16x8*)(w2r + (size_t)row * 128 + seg);
        bf16x8* lp = (bf16x8*)&Bs[0][row][seg];
#pragma unroll
        for (int u = 0; u < 4; u++) lp[u] = gp[u];
    }
    // --- B2s[o][i] = bf16(b2[i*64+o]) ---
    for (int g = tid; g < 4096; g += 256) {
        B2s[g & 63][g >> 6] = __float2bfloat16(b2[g]);
    }
    __syncthreads();  // eas/w1s/b1s ready
    // --- hidden[e][k] = relu(b1[k] + ea[e]·w1[k]) as bf16 ---
    {
        int e = tid & 63, k0 = (tid >> 6) * 32;
        int ge = e0 + e;
        float a0 = eas[e][0], a1 = eas[e][1], a2 = eas[e][2], a3 = eas[e][3];
        bool valid = ge < NE;
        for (int k = k0; k < k0 + 32; k++) {
            float v = b1s[k] + a0 * w1s[k][0] + a1 * w1s[k][1] + a2 * w1s[k][2] + a3 * w1s[k][3];
            v = valid ? fmaxf(v, 0.f) : 0.f;
            hid[e][k] = __float2bfloat16(v);
        }
    }
    __syncthreads();  // hid, hsrc, Bs[0], B2s ready

    int lane = tid & 63;
    int w = tid >> 6;          // wave id: edge rows w*16..w*16+15
    int n = lane & 15, q = lane >> 4;
    int erow = w * 16 + n;

    // A-fragments: hidden (i-invariant) and hsrc (for b2 pass)
    bf16x8 afr[4];
#pragma unroll
    for (int ks = 0; ks < 4; ks++) afr[ks] = *(const bf16x8*)&hid[erow][ks * 32 + q * 8];
    bf16x8 ah[2];
#pragma unroll
    for (int ks = 0; ks < 2; ks++) ah[ks] = *(const bf16x8*)&hsrc[erow][ks * 32 + q * 8];

    f32x4 acc[4];
#pragma unroll
    for (int ct = 0; ct < 4; ct++) acc[ct] = (f32x4){0.f, 0.f, 0.f, 0.f};

    for (int i = 0; i < 64; i++) {
        __syncthreads();  // Bs[i&1] staged; all waves done reading Bs[(i+1)&1]
        if (i + 1 < 64) {
            int row = tid >> 2, seg = (tid & 3) * 32;
            const bf16x8* gp = (const bf16x8*)(w2r + (size_t)(i + 1) * 8192 + row * 128 + seg);
            bf16x8* lp = (bf16x8*)&Bs[(i + 1) & 1][row][seg];
#pragma unroll
            for (int u = 0; u < 4; u++) lp[u] = gp[u];
        }
        f32x4 S[4];
#pragma unroll
        for (int ct = 0; ct < 4; ct++) S[ct] = (f32x4){0.f, 0.f, 0.f, 0.f};
#pragma unroll
        for (int ks = 0; ks < 4; ks++) {
#pragma unroll
            for (int ct = 0; ct < 4; ct++) {
                bf16x8 bfr = *(const bf16x8*)&Bs[i & 1][ct * 16 + n][ks * 32 + q * 8];
                S[ct] = __builtin_amdgcn_mfma_f32_16x16x32_bf16(afr[ks], bfr, S[ct], 0, 0, 0);
            }
        }
        float hm[4];
#pragma unroll
        for (int r = 0; r < 4; r++) hm[r] = __bfloat162float(hsrc[w * 16 + q * 4 + r][i]);
#pragma unroll
        for (int ct = 0; ct < 4; ct++)
#pragma unroll
            for (int r = 0; r < 4; r++) acc[ct][r] += hm[r] * S[ct][r];
    }

    // b2 pass: acc += hsrc(bf16) @ B2s
    {
        f32x4 S2[4];
#pragma unroll
        for (int ct = 0; ct < 4; ct++) S2[ct] = (f32x4){0.f, 0.f, 0.f, 0.f};
#pragma unroll
        for (int ks = 0; ks < 2; ks++) {
#pragma unroll
            for (int ct = 0; ct < 4; ct++) {
                bf16x8 bfr = *(const bf16x8*)&B2s[ct * 16 + n][ks * 32 + q * 8];
                S2[ct] = __builtin_amdgcn_mfma_f32_16x16x32_bf16(ah[ks], bfr, S2[ct], 0, 0, 0);
            }
        }
#pragma unroll
        for (int ct = 0; ct < 4; ct++)
#pragma unroll
            for (int r = 0; r < 4; r++) acc[ct][r] += S2[ct][r];
    }

    // scatter: C layout col=lane&15 (o within tile), row=q*4+reg (e within wave tile)
#pragma unroll
    for (int r = 0; r < 4; r++) {
        int e = w * 16 + q * 4 + r;
        if (e0 + e < NE) {
            int dn = didx[e];
#pragma unroll
            for (int ct = 0; ct < 4; ct++)
                atomicAdd(&agg[(size_t)dn * 64 + ct * 16 + n], acc[ct][r]);
        }
    }
}

// ---------------- degree ----------------
__global__ void deg_kernel(const int* __restrict__ ei, float* __restrict__ deg) {
    int e = blockIdx.x * 256 + threadIdx.x;
    if (e < NE) atomicAdd(&deg[ei[NE + e]], 1.0f);
}
__global__ void invdeg_kernel(float* deg) {
    int n = blockIdx.x * 256 + threadIdx.x;
    if (n < NN) deg[n] = 1.0f / fmaxf(deg[n], 1.0f);
}

// ---------------- conv (in-place into agg): agg = relu(out @ conv_root + agg*invdeg + bias) ----------------
__global__ void conv_kernel(const float* __restrict__ out, float* __restrict__ agg,
                            const float* __restrict__ invdeg, const float* __restrict__ root,
                            const float* __restrict__ cbias) {
    int grp = threadIdx.x >> 6;
    int d = threadIdx.x & 63;
    int n = blockIdx.x * 4 + grp;
    __shared__ float s[4][64];
    if (n < NN) s[grp][d] = out[n * D + d];
    __syncthreads();
    if (n >= NN) return;
    float acc = 0.f;
    const float* sr = s[grp];
#pragma unroll 8
    for (int k = 0; k < 64; k++) acc += sr[k] * root[k * D + d];
    agg[n * D + d] = fmaxf(acc + agg[n * D + d] * invdeg[n] + cbias[d], 0.f);
}

// ---------------- GRU: h = GRUCell(m, h); weights pre-transposed [64][192] ----------------
__global__ __launch_bounds__(256) void gru_kernel(const float* __restrict__ m, float* __restrict__ h,
                                                  const float* __restrict__ wihT,
                                                  const float* __restrict__ whhT,
                                                  const float* __restrict__ bih,
                                                  const float* __restrict__ bhh) {
    int tid = threadIdx.x;
    int grp = tid >> 6;
    int j = tid & 63;
    int n0 = blockIdx.x * 16;
    int nd0 = grp * 4;
    __shared__ float ms[16][64];
    __shared__ float hs[16][64];
    for (int i = tid; i < 16 * 64; i += 256) {
        int nd = i >> 6, dd = i & 63;
        ms[nd][dd] = m[(n0 + nd) * D + dd];
        hs[nd][dd] = h[(n0 + nd) * D + dd];
    }
    __syncthreads();
    float air[4] = {}, aiz[4] = {}, ain[4] = {};
    float ahr[4] = {}, ahz[4] = {}, ahn[4] = {};
#pragma unroll 4
    for (int k = 0; k < 64; k++) {
        float wr = wihT[k * 192 + j];
        float wz = wihT[k * 192 + 64 + j];
        float wn = wihT[k * 192 + 128 + j];
        float vr = whhT[k * 192 + j];
        float vz = whhT[k * 192 + 64 + j];
        float vn = whhT[k * 192 + 128 + j];
#pragma unroll
        for (int q = 0; q < 4; q++) {
            float mv = ms[nd0 + q][k], hv = hs[nd0 + q][k];
            air[q] = fmaf(mv, wr, air[q]);
            aiz[q] = fmaf(mv, wz, aiz[q]);
            ain[q] = fmaf(mv, wn, ain[q]);
            ahr[q] = fmaf(hv, vr, ahr[q]);
            ahz[q] = fmaf(hv, vz, ahz[q]);
            ahn[q] = fmaf(hv, vn, ahn[q]);
        }
    }
    float br = bih[j], bz = bih[64 + j], bn = bih[128 + j];
    float cr = bhh[j], cz = bhh[64 + j], cn = bhh[128 + j];
#pragma unroll
    for (int q = 0; q < 4; q++) {
        float r = sigmoidf(air[q] + br + ahr[q] + cr);
        float z = sigmoidf(aiz[q] + bz + ahz[q] + cz);
        float nn2 = tanhf(ain[q] + bn + r * (ahn[q] + cn));
        float hv = hs[nd0 + q][j];
        h[(n0 + nd0 + q) * D + j] = (1.f - z) * nn2 + z * hv;
    }
}

// ---------------- graph starts (batch sorted) ----------------
__global__ void starts_kernel(const int* __restrict__ batch, int* __restrict__ start) {
    int n = blockIdx.x * 256 + threadIdx.x;
    if (n >= NN) return;
    int b = batch[n];
    int bp = (n == 0) ? -1 : batch[n - 1];
    for (int g = bp + 1; g <= b; g++) start[g] = n;
    if (n == NN - 1) {
        for (int g = b + 1; g <= NG; g++) start[g] = NN;
    }
}

// ---------------- Set2Set LSTM step ----------------
__global__ void s2s_lstm_kernel(const float* __restrict__ qstar, float* __restrict__ hh,
                                float* __restrict__ cc, const float* __restrict__ wihT,
                                const float* __restrict__ whhT, const float* __restrict__ bih,
                                const float* __restrict__ bhh) {
    int g = blockIdx.x;
    int j = threadIdx.x;  // 256
    __shared__ float q[128], hsh[64], gates[256];
    if (j < 128) q[j] = qstar[g * 128 + j];
    if (j < 64) hsh[j] = hh[g * 64 + j];
    __syncthreads();
    float acc = bih[j] + bhh[j];
#pragma unroll 8
    for (int k = 0; k < 128; k++) acc = fmaf(q[k], wihT[k * 256 + j], acc);
#pragma unroll 8
    for (int k = 0; k < 64; k++) acc = fmaf(hsh[k], whhT[k * 256 + j], acc);
    gates[j] = acc;
    __syncthreads();
    if (j < 64) {
        float gi = gates[j], gf = gates[64 + j], gg = gates[128 + j], go = gates[192 + j];
        float c2 = sigmoidf(gf) * cc[g * 64 + j] + sigmoidf(gi) * tanhf(gg);
        float h2 = sigmoidf(go) * tanhf(c2);
        cc[g * 64 + j] = c2;
        hh[g * 64 + j] = h2;
    }
}

// ---------------- Set2Set attention + pooling; writes q_star ----------------
__global__ void s2s_attn_kernel(const float* __restrict__ out, const float* __restrict__ hh,
                                const int* __restrict__ start, float* __restrict__ qstar) {
    int g = blockIdx.x;
    int d = threadIdx.x;  // 64
    int n0 = start[g], n1 = start[g + 1];
    float hd = hh[g * 64 + d];
    float mx = -INFINITY;
    for (int n = n0; n < n1; n++) {
        float p = out[n * D + d] * hd;
#pragma unroll
        for (int off = 32; off; off >>= 1) p += __shfl_xor(p, off);
        mx = fmaxf(mx, p);
    }
    float sexp = 0.f, racc = 0.f;
    for (int n = n0; n < n1; n++) {
        float ond = out[n * D + d];
        float p = ond * hd;
#pragma unroll
        for (int off = 32; off; off >>= 1) p += __shfl_xor(p, off);
        float a = expf(p - mx);
        sexp += a;
        racc = fmaf(a, ond, racc);
    }
    float r = racc / (sexp + 1e-16f);
    qstar[g * 128 + d] = hd;
    qstar[g * 128 + 64 + d] = r;
}

// ---------------- head ----------------
__global__ void final_kernel(const float* __restrict__ qstar, const float* __restrict__ w1,
                             const float* __restrict__ b1, const float* __restrict__ w2,
                             const float* __restrict__ b2, float* __restrict__ y) {
    int g = blockIdx.x;
    int d = threadIdx.x;  // 64
    __shared__ float q[128];
    q[d] = qstar[g * 128 + d];
    q[64 + d] = qstar[g * 128 + 64 + d];
    __syncthreads();
    float acc = b1[d];
#pragma unroll 8
    for (int k = 0; k < 128; k++) acc = fmaf(q[k], w1[d * 128 + k], acc);
    acc = fmaxf(acc, 0.f);
    float p = acc * w2[d];
#pragma unroll
    for (int off = 32; off; off >>= 1) p += __shfl_xor(p, off);
    if (d == 0) y[g] = p + b2[0];
}

extern "C" void kernel_launch(void* const* d_in, const int* in_sizes, int n_in,
                              void* d_out, int out_size, void* d_ws, size_t ws_size,
                              hipStream_t stream) {
    (void)in_sizes; (void)n_in; (void)out_size; (void)ws_size;
    const float* x = (const float*)d_in[0];
    const int* edge_index = (const int*)d_in[1];
    const float* edge_attr = (const float*)d_in[2];
    const int* batch = (const int*)d_in[3];
    const float* lin0_w = (const float*)d_in[4];
    const float* lin0_b = (const float*)d_in[5];
    const float* nn_w1 = (const float*)d_in[6];
    const float* nn_b1 = (const float*)d_in[7];
    const float* nn_w2 = (const float*)d_in[8];
    const float* nn_b2 = (const float*)d_in[9];
    const float* conv_root = (const float*)d_in[10];
    const float* conv_bias = (const float*)d_in[11];
    const float* gru_w_ih = (const float*)d_in[12];
    const float* gru_w_hh = (const float*)d_in[13];
    const float* gru_b_ih = (const float*)d_in[14];
    const float* gru_b_hh = (const float*)d_in[15];
    const float* s2s_w_ih = (const float*)d_in[16];
    const float* s2s_w_hh = (const float*)d_in[17];
    const float* s2s_b_ih = (const float*)d_in[18];
    const float* s2s_b_hh = (const float*)d_in[19];
    const float* lin1_w = (const float*)d_in[20];
    const float* lin1_b = (const float*)d_in[21];
    const float* lin2_w = (const float*)d_in[22];
    const float* lin2_b = (const float*)d_in[23];
    float* y = (float*)d_out;

    char* ws = (char*)d_ws;
    size_t off = 0;
    auto alloc = [&](size_t bytes) {
        void* p = ws + off;
        off = (off + bytes + 255) & ~(size_t)255;
        return p;
    };
    // layout identical in total size to the round-2 passing layout (~28.2 MB)
    float* h = (float*)alloc((size_t)NN * D * 4);
    float* agg = (float*)alloc((size_t)NN * D * 4);
    float* invdeg = (float*)alloc((size_t)NN * 4);
    int* start = (int*)alloc((size_t)(NG + 1) * 4);
    float* qstar = (float*)alloc((size_t)NG * 128 * 4);   // 1 MB; ALIASED as w2r during MP phase
    float* hh = (float*)alloc((size_t)NG * 64 * 4);
    float* ccv = (float*)alloc((size_t)NG * 64 * 4);
    float* gruT_ih = (float*)alloc(192 * 64 * 4);
    float* gruT_hh = (float*)alloc(192 * 64 * 4);
    float* s2sT_ih = (float*)alloc(256 * 128 * 4);
    float* s2sT_hh = (float*)alloc(256 * 64 * 4);
    // w2r (bf16 nn_w2, 64*8192*2 = 1048576 B) aliases qstar (2048*128*4 = 1048576 B):
    // w2r is only read during the MP loop; qstar is zeroed/used only after it.
    __hip_bfloat16* w2r = (__hip_bfloat16*)qstar;

    // prep
    zero_kernel<<<(NN + 255) / 256, 256, 0, stream>>>(invdeg, NN);
    transpose_kernel<<<(192 * 64 + 255) / 256, 256, 0, stream>>>(gru_w_ih, gruT_ih, 192, 64);
    transpose_kernel<<<(192 * 64 + 255) / 256, 256, 0, stream>>>(gru_w_hh, gruT_hh, 192, 64);
    transpose_kernel<<<(256 * 128 + 255) / 256, 256, 0, stream>>>(s2s_w_ih, s2sT_ih, 256, 128);
    transpose_kernel<<<(256 * 64 + 255) / 256, 256, 0, stream>>>(s2s_w_hh, s2sT_hh, 256, 64);
    cvt_bf16_kernel<<<(64 * 8192 + 255) / 256, 256, 0, stream>>>(nn_w2, w2r, 64 * 8192);
    lin0_kernel<<<NN / 4, 256, 0, stream>>>(x, lin0_w, lin0_b, h);
    deg_kernel<<<(NE + 255) / 256, 256, 0, stream>>>(edge_index, invdeg);
    invdeg_kernel<<<(NN + 255) / 256, 256, 0, stream>>>(invdeg);
    starts_kernel<<<(NN + 255) / 256, 256, 0, stream>>>(batch, start);

    // 3 message-passing + GRU iterations
    for (int it = 0; it < 3; it++) {
        zero_kernel<<<(NN * D + 255) / 256, 256, 0, stream>>>(agg, NN * D);
        msg_mfma_kernel<<<(NE + EB - 1) / EB, 256, 0, stream>>>(
            h, edge_attr, nn_w1, nn_b1, w2r, nn_b2, edge_index, agg);
        conv_kernel<<<NN / 4, 256, 0, stream>>>(h, agg, invdeg, conv_root, conv_bias);
        gru_kernel<<<NN / 16, 256, 0, stream>>>(agg, h, gruT_ih, gruT_hh, gru_b_ih, gru_b_hh);
    }

    // Set2Set (qstar region no longer needed as w2r)
    zero_kernel<<<(NG * 128 + 255) / 256, 256, 0, stream>>>(qstar, NG * 128);
    zero_kernel<<<(NG * 64 + 255) / 256, 256, 0, stream>>>(hh, NG * 64);
    zero_kernel<<<(NG * 64 + 255) / 256, 256, 0, stream>>>(ccv, NG * 64);
    for (int t = 0; t < 3; t++) {
        s2s_lstm_kernel<<<NG, 256, 0, stream>>>(qstar, hh, ccv, s2sT_ih, s2sT_hh, s2s_b_ih, s2s_b_hh);
        s2s_attn_kernel<<<NG, 64, 0, stream>>>(h, hh, start, qstar);
    }
    final_kernel<<<NG, 64, 0, stream>>>(qstar, lin1_w, lin1_b, lin2_w, lin2_b, y);
}

// Round 4
// 927.487 us; speedup vs baseline: 10.4049x; 1.4278x over previous
//
#include <hip/hip_runtime.h>
#include <hip/hip_bf16.h>

#define NN 50000    // nodes
#define NE 100000   // edges
#define NG 2048     // graphs
#define NF 14
#define D 64
#define EB 128      // edges per block in msg kernel (2 row-tiles per wave)

typedef __attribute__((ext_vector_type(8))) short bf16x8;
typedef __attribute__((ext_vector_type(4))) float f32x4;

__device__ __forceinline__ float sigmoidf(float x) { return 1.f / (1.f + expf(-x)); }

// ---------------- utility ----------------
__global__ void cvt_bf16_kernel(const float* __restrict__ src, __hip_bfloat16* __restrict__ dst, int n) {
    int i = blockIdx.x * 256 + threadIdx.x;
    if (i < n) dst[i] = __float2bfloat16(src[i]);
}

// dst[c*rows + r] = src[r*cols + c]
__global__ void transpose_kernel(const float* __restrict__ src, float* __restrict__ dst,
                                 int rows, int cols) {
    int idx = blockIdx.x * 256 + threadIdx.x;
    if (idx < rows * cols) {
        int r = idx / cols, c = idx - r * cols;
        dst[c * rows + r] = src[idx];
    }
}

// ---------------- lin0: out = relu(x @ lin0_w.T + b) ----------------
__global__ void lin0_kernel(const float* __restrict__ x, const float* __restrict__ w,
                            const float* __restrict__ b, float* __restrict__ out) {
    int grp = threadIdx.x >> 6;
    int d = threadIdx.x & 63;
    int n = blockIdx.x * 4 + grp;
    __shared__ float xs[4][NF];
    int t = threadIdx.x;
    if (t < 4 * NF) {
        int r = t / NF, c = t - r * NF;
        int nn2 = blockIdx.x * 4 + r;
        xs[r][c] = (nn2 < NN) ? x[nn2 * NF + c] : 0.f;
    }
    __syncthreads();
    if (n >= NN) return;
    float acc = b[d];
#pragma unroll
    for (int k = 0; k < NF; k++) acc += xs[grp][k] * w[d * NF + k];
    out[n * D + d] = fmaxf(acc, 0.f);
}

// ================= MFMA fused message kernel (EB=128, 2 row-tiles/wave) =================
// agg[dst_e, o] += sum_i h[src_e, i] * ( hidden[e,:] . W2[i*64+o, :] )  + sum_i h[src_e,i]*b2[i*64+o]
__global__ __launch_bounds__(256, 2) void msg_mfma_kernel(
    const float* __restrict__ h, const float* __restrict__ ea,
    const float* __restrict__ w1, const float* __restrict__ b1,
    const __hip_bfloat16* __restrict__ w2r,  // bf16 copy of nn_w2 [4096][128] row-major
    const float* __restrict__ b2, const int* __restrict__ ei,
    float* __restrict__ agg)
{
    // union pool: hid[EB][136] (preamble only) aliases Bs[2][64][136] (main loop)
    __shared__ __align__(16) char upool[EB * 136 * 2];  // 34816 B
    __hip_bfloat16 (*hid)[136] = (__hip_bfloat16(*)[136])upool;
    __hip_bfloat16 (*Bs)[64][136] = (__hip_bfloat16(*)[64][136])upool;
    __shared__ __align__(16) __hip_bfloat16 hsrc[EB][72];  // 18432 B
    __shared__ __align__(16) __hip_bfloat16 B2s[64][72];   // 9216 B
    __shared__ float w1s[128][4];
    __shared__ float b1s[128];
    __shared__ float eas[EB][4];
    __shared__ int didx[EB];

    int tid = threadIdx.x;
    int e0 = blockIdx.x * EB;

    // --- stage ea, w1, b1, didx ---
    for (int idx = tid; idx < EB * 4; idx += 256) {
        int e = idx >> 2, j = idx & 3;
        int ge = e0 + e;
        eas[e][j] = (ge < NE) ? ea[ge * 4 + j] : 0.f;
    }
    if (tid < 128) {
        w1s[tid][0] = w1[tid * 4 + 0]; w1s[tid][1] = w1[tid * 4 + 1];
        w1s[tid][2] = w1[tid * 4 + 2]; w1s[tid][3] = w1[tid * 4 + 3];
        b1s[tid] = b1[tid];
    }
    if (tid < EB) didx[tid] = (e0 + tid < NE) ? ei[NE + e0 + tid] : -1;
    // --- gather h[src] -> hsrc bf16 (each thread: half a row) ---
    {
        int e = tid >> 1, half = (tid & 1) * 32;
        int ge = e0 + e;
        int src = (ge < NE) ? ei[ge] : 0;
        const float4* hp = (const float4*)(h + (size_t)src * 64 + half);
#pragma unroll
        for (int u = 0; u < 8; u++) {
            float4 v = (ge < NE) ? hp[u] : make_float4(0.f, 0.f, 0.f, 0.f);
            union { __hip_bfloat16 b[4]; uint2 uu; } pk;
            pk.b[0] = __float2bfloat16(v.x); pk.b[1] = __float2bfloat16(v.y);
            pk.b[2] = __float2bfloat16(v.z); pk.b[3] = __float2bfloat16(v.w);
            *(uint2*)&hsrc[e][half + u * 4] = pk.uu;
        }
    }
    // --- B2s[o][i] = bf16(b2[i*64+o]) ---
    for (int g = tid; g < 4096; g += 256) {
        B2s[g & 63][g >> 6] = __float2bfloat16(b2[g]);
    }
    __syncthreads();  // eas/w1s/b1s ready
    // --- hid[e][k] = relu(b1[k] + ea[e]·w1[k]) bf16, packed stores ---
    {
        int e = tid & 127, kb = (tid >> 7) * 64;
        float a0 = eas[e][0], a1 = eas[e][1], a2 = eas[e][2], a3 = eas[e][3];
        for (int k = kb; k < kb + 64; k += 4) {
            union { __hip_bfloat16 b[4]; uint2 uu; } pk;
#pragma unroll
            for (int u = 0; u < 4; u++) {
                float v = b1s[k + u] + a0 * w1s[k + u][0] + a1 * w1s[k + u][1] +
                          a2 * w1s[k + u][2] + a3 * w1s[k + u][3];
                pk.b[u] = __float2bfloat16(fmaxf(v, 0.f));
            }
            *(uint2*)&hid[e][k] = pk.uu;
        }
    }
    __syncthreads();  // hid ready

    int lane = tid & 63;
    int w = tid >> 6;            // wave id; wave owns edge rows w*32 .. w*32+31
    int n = lane & 15, q = lane >> 4;
    int er0 = w * 32;

    // A-fragments (i-invariant) into registers
    bf16x8 afr[2][4];
#pragma unroll
    for (int rt = 0; rt < 2; rt++)
#pragma unroll
        for (int ks = 0; ks < 4; ks++)
            afr[rt][ks] = *(const bf16x8*)&hid[er0 + rt * 16 + n][ks * 32 + q * 8];
    __syncthreads();  // hid dead; pool becomes Bs

    // stage Bs[0] (slice i=0)
    {
        int row = tid >> 2, seg = (tid & 3) * 32;
        const bf16x8* gp = (const bf16x8*)(w2r + (size_t)row * 128 + seg);
        bf16x8* lp = (bf16x8*)&Bs[0][row][seg];
#pragma unroll
        for (int u = 0; u < 4; u++) lp[u] = gp[u];
    }
    __syncthreads();  // Bs[0] ready

    f32x4 acc[2][4];
#pragma unroll
    for (int rt = 0; rt < 2; rt++)
#pragma unroll
        for (int ct = 0; ct < 4; ct++) acc[rt][ct] = (f32x4){0.f, 0.f, 0.f, 0.f};

    int srow = tid >> 2, sseg = (tid & 3) * 32;
    for (int i = 0; i < 64; i++) {
        const int cur = i & 1;
        // early global load of next slice into registers
        bf16x8 pre[4];
        if (i + 1 < 64) {
            const bf16x8* gp = (const bf16x8*)(w2r + (size_t)(i + 1) * 8192 + srow * 128 + sseg);
#pragma unroll
            for (int u = 0; u < 4; u++) pre[u] = gp[u];
        }
        // MFMA: S[rt][ct] over 4 k-steps; B-frag shared across row-tiles
        f32x4 S[2][4];
#pragma unroll
        for (int rt = 0; rt < 2; rt++)
#pragma unroll
            for (int ct = 0; ct < 4; ct++) S[rt][ct] = (f32x4){0.f, 0.f, 0.f, 0.f};
#pragma unroll
        for (int ks = 0; ks < 4; ks++) {
#pragma unroll
            for (int ct = 0; ct < 4; ct++) {
                bf16x8 bfr = *(const bf16x8*)&Bs[cur][ct * 16 + n][ks * 32 + q * 8];
                S[0][ct] = __builtin_amdgcn_mfma_f32_16x16x32_bf16(afr[0][ks], bfr, S[0][ct], 0, 0, 0);
                S[1][ct] = __builtin_amdgcn_mfma_f32_16x16x32_bf16(afr[1][ks], bfr, S[1][ct], 0, 0, 0);
            }
        }
        // fixup: acc += h[src,i] * S
        float hm[2][4];
#pragma unroll
        for (int rt = 0; rt < 2; rt++)
#pragma unroll
            for (int r = 0; r < 4; r++)
                hm[rt][r] = __bfloat162float(hsrc[er0 + rt * 16 + q * 4 + r][i]);
#pragma unroll
        for (int rt = 0; rt < 2; rt++)
#pragma unroll
            for (int ct = 0; ct < 4; ct++)
#pragma unroll
                for (int r = 0; r < 4; r++) acc[rt][ct][r] += hm[rt][r] * S[rt][ct][r];
        // late LDS store of next slice
        if (i + 1 < 64) {
            bf16x8* lp = (bf16x8*)&Bs[cur ^ 1][srow][sseg];
#pragma unroll
            for (int u = 0; u < 4; u++) lp[u] = pre[u];
        }
        __syncthreads();
    }

    // b2 pass: acc += hsrc(bf16) @ B2s
    {
        f32x4 S2[2][4];
#pragma unroll
        for (int rt = 0; rt < 2; rt++)
#pragma unroll
            for (int ct = 0; ct < 4; ct++) S2[rt][ct] = (f32x4){0.f, 0.f, 0.f, 0.f};
#pragma unroll
        for (int ks = 0; ks < 2; ks++) {
            bf16x8 ah0 = *(const bf16x8*)&hsrc[er0 + n][ks * 32 + q * 8];
            bf16x8 ah1 = *(const bf16x8*)&hsrc[er0 + 16 + n][ks * 32 + q * 8];
#pragma unroll
            for (int ct = 0; ct < 4; ct++) {
                bf16x8 bfr = *(const bf16x8*)&B2s[ct * 16 + n][ks * 32 + q * 8];
                S2[0][ct] = __builtin_amdgcn_mfma_f32_16x16x32_bf16(ah0, bfr, S2[0][ct], 0, 0, 0);
                S2[1][ct] = __builtin_amdgcn_mfma_f32_16x16x32_bf16(ah1, bfr, S2[1][ct], 0, 0, 0);
            }
        }
#pragma unroll
        for (int rt = 0; rt < 2; rt++)
#pragma unroll
            for (int ct = 0; ct < 4; ct++)
#pragma unroll
                for (int r = 0; r < 4; r++) acc[rt][ct][r] += S2[rt][ct][r];
    }

    // scatter: C layout col=lane&15 (o within ct tile), row=q*4+reg (edge within row-tile)
#pragma unroll
    for (int rt = 0; rt < 2; rt++)
#pragma unroll
        for (int r = 0; r < 4; r++) {
            int e = er0 + rt * 16 + q * 4 + r;
            if (e0 + e < NE) {
                int dn = didx[e];
#pragma unroll
                for (int ct = 0; ct < 4; ct++)
                    atomicAdd(&agg[(size_t)dn * 64 + ct * 16 + n], acc[rt][ct][r]);
            }
        }
}

// ---------------- degree ----------------
__global__ void deg_kernel(const int* __restrict__ ei, float* __restrict__ deg) {
    int e = blockIdx.x * 256 + threadIdx.x;
    if (e < NE) atomicAdd(&deg[ei[NE + e]], 1.0f);
}
__global__ void invdeg_kernel(float* deg) {
    int n = blockIdx.x * 256 + threadIdx.x;
    if (n < NN) deg[n] = 1.0f / fmaxf(deg[n], 1.0f);
}

// ---------------- fused conv + GRU: h = GRUCell(relu(h@root + agg*invdeg + cbias), h) ----------------
// 16 nodes/block; h updated in place (each block touches only its own rows).
__global__ __launch_bounds__(256) void conv_gru_kernel(
    float* __restrict__ h, const float* __restrict__ agg, const float* __restrict__ invdeg,
    const float* __restrict__ root, const float* __restrict__ cbias,
    const float* __restrict__ wihT, const float* __restrict__ whhT,
    const float* __restrict__ bih, const float* __restrict__ bhh)
{
    int tid = threadIdx.x;
    int grp = tid >> 6;
    int j = tid & 63;
    int n0 = blockIdx.x * 16;
    int nd0 = grp * 4;
    __shared__ float hs[16][64];
    __shared__ float ms[16][68];
    for (int i = tid; i < 1024; i += 256) {
        int nd = i >> 6, dd = i & 63;
        hs[nd][dd] = h[(n0 + nd) * D + dd];
    }
    __syncthreads();
    // conv: m for nodes nd0..nd0+3, column j
    float mm[4] = {};
#pragma unroll 8
    for (int k = 0; k < 64; k++) {
        float rv = root[k * 64 + j];
#pragma unroll
        for (int q = 0; q < 4; q++) mm[q] += hs[nd0 + q][k] * rv;
    }
    float cb = cbias[j];
#pragma unroll
    for (int q = 0; q < 4; q++) {
        int nn2 = n0 + nd0 + q;
        float v = mm[q] + agg[(size_t)nn2 * 64 + j] * invdeg[nn2] + cb;
        ms[nd0 + q][j] = fmaxf(v, 0.f);
    }
    __syncthreads();
    // GRU
    float air[4] = {}, aiz[4] = {}, ain[4] = {};
    float ahr[4] = {}, ahz[4] = {}, ahn[4] = {};
#pragma unroll 4
    for (int k = 0; k < 64; k++) {
        float wr = wihT[k * 192 + j];
        float wz = wihT[k * 192 + 64 + j];
        float wn = wihT[k * 192 + 128 + j];
        float vr = whhT[k * 192 + j];
        float vz = whhT[k * 192 + 64 + j];
        float vn = whhT[k * 192 + 128 + j];
#pragma unroll
        for (int q = 0; q < 4; q++) {
            float mv = ms[nd0 + q][k], hv = hs[nd0 + q][k];
            air[q] = fmaf(mv, wr, air[q]);
            aiz[q] = fmaf(mv, wz, aiz[q]);
            ain[q] = fmaf(mv, wn, ain[q]);
            ahr[q] = fmaf(hv, vr, ahr[q]);
            ahz[q] = fmaf(hv, vz, ahz[q]);
            ahn[q] = fmaf(hv, vn, ahn[q]);
        }
    }
    float br = bih[j], bz = bih[64 + j], bn = bih[128 + j];
    float cr = bhh[j], cz = bhh[64 + j], cn = bhh[128 + j];
#pragma unroll
    for (int q = 0; q < 4; q++) {
        float r = sigmoidf(air[q] + br + ahr[q] + cr);
        float z = sigmoidf(aiz[q] + bz + ahz[q] + cz);
        float nn2 = tanhf(ain[q] + bn + r * (ahn[q] + cn));
        float hv = hs[nd0 + q][j];
        h[(n0 + nd0 + q) * D + j] = (1.f - z) * nn2 + z * hv;
    }
}

// ---------------- graph starts (batch sorted) ----------------
__global__ void starts_kernel(const int* __restrict__ batch, int* __restrict__ start) {
    int n = blockIdx.x * 256 + threadIdx.x;
    if (n >= NN) return;
    int b = batch[n];
    int bp = (n == 0) ? -1 : batch[n - 1];
    for (int g = bp + 1; g <= b; g++) start[g] = n;
    if (n == NN - 1) {
        for (int g = b + 1; g <= NG; g++) start[g] = NN;
    }
}

// ---------------- Set2Set LSTM step ----------------
__global__ void s2s_lstm_kernel(const float* __restrict__ qstar, float* __restrict__ hh,
                                float* __restrict__ cc, const float* __restrict__ wihT,
                                const float* __restrict__ whhT, const float* __restrict__ bih,
                                const float* __restrict__ bhh) {
    int g = blockIdx.x;
    int j = threadIdx.x;  // 256
    __shared__ float q[128], hsh[64], gates[256];
    if (j < 128) q[j] = qstar[g * 128 + j];
    if (j < 64) hsh[j] = hh[g * 64 + j];
    __syncthreads();
    float acc = bih[j] + bhh[j];
#pragma unroll 8
    for (int k = 0; k < 128; k++) acc = fmaf(q[k], wihT[k * 256 + j], acc);
#pragma unroll 8
    for (int k = 0; k < 64; k++) acc = fmaf(hsh[k], whhT[k * 256 + j], acc);
    gates[j] = acc;
    __syncthreads();
    if (j < 64) {
        float gi = gates[j], gf = gates[64 + j], gg = gates[128 + j], go = gates[192 + j];
        float c2 = sigmoidf(gf) * cc[g * 64 + j] + sigmoidf(gi) * tanhf(gg);
        float h2 = sigmoidf(go) * tanhf(c2);
        cc[g * 64 + j] = c2;
        hh[g * 64 + j] = h2;
    }
}

// ---------------- Set2Set attention + pooling; writes q_star ----------------
__global__ void s2s_attn_kernel(const float* __restrict__ out, const float* __restrict__ hh,
                                const int* __restrict__ start, float* __restrict__ qstar) {
    int g = blockIdx.x;
    int d = threadIdx.x;  // 64
    int n0 = start[g], n1 = start[g + 1];
    float hd = hh[g * 64 + d];
    float mx = -INFINITY;
    for (int n = n0; n < n1; n++) {
        float p = out[n * D + d] * hd;
#pragma unroll
        for (int off = 32; off; off >>= 1) p += __shfl_xor(p, off);
        mx = fmaxf(mx, p);
    }
    float sexp = 0.f, racc = 0.f;
    for (int n = n0; n < n1; n++) {
        float ond = out[n * D + d];
        float p = ond * hd;
#pragma unroll
        for (int off = 32; off; off >>= 1) p += __shfl_xor(p, off);
        float a = expf(p - mx);
        sexp += a;
        racc = fmaf(a, ond, racc);
    }
    float r = racc / (sexp + 1e-16f);
    qstar[g * 128 + d] = hd;
    qstar[g * 128 + 64 + d] = r;
}

// ---------------- head ----------------
__global__ void final_kernel(const float* __restrict__ qstar, const float* __restrict__ w1,
                             const float* __restrict__ b1, const float* __restrict__ w2,
                             const float* __restrict__ b2, float* __restrict__ y) {
    int g = blockIdx.x;
    int d = threadIdx.x;  // 64
    __shared__ float q[128];
    q[d] = qstar[g * 128 + d];
    q[64 + d] = qstar[g * 128 + 64 + d];
    __syncthreads();
    float acc = b1[d];
#pragma unroll 8
    for (int k = 0; k < 128; k++) acc = fmaf(q[k], w1[d * 128 + k], acc);
    acc = fmaxf(acc, 0.f);
    float p = acc * w2[d];
#pragma unroll
    for (int off = 32; off; off >>= 1) p += __shfl_xor(p, off);
    if (d == 0) y[g] = p + b2[0];
}

extern "C" void kernel_launch(void* const* d_in, const int* in_sizes, int n_in,
                              void* d_out, int out_size, void* d_ws, size_t ws_size,
                              hipStream_t stream) {
    (void)in_sizes; (void)n_in; (void)out_size; (void)ws_size;
    const float* x = (const float*)d_in[0];
    const int* edge_index = (const int*)d_in[1];
    const float* edge_attr = (const float*)d_in[2];
    const int* batch = (const int*)d_in[3];
    const float* lin0_w = (const float*)d_in[4];
    const float* lin0_b = (const float*)d_in[5];
    const float* nn_w1 = (const float*)d_in[6];
    const float* nn_b1 = (const float*)d_in[7];
    const float* nn_w2 = (const float*)d_in[8];
    const float* nn_b2 = (const float*)d_in[9];
    const float* conv_root = (const float*)d_in[10];
    const float* conv_bias = (const float*)d_in[11];
    const float* gru_w_ih = (const float*)d_in[12];
    const float* gru_w_hh = (const float*)d_in[13];
    const float* gru_b_ih = (const float*)d_in[14];
    const float* gru_b_hh = (const float*)d_in[15];
    const float* s2s_w_ih = (const float*)d_in[16];
    const float* s2s_w_hh = (const float*)d_in[17];
    const float* s2s_b_ih = (const float*)d_in[18];
    const float* s2s_b_hh = (const float*)d_in[19];
    const float* lin1_w = (const float*)d_in[20];
    const float* lin1_b = (const float*)d_in[21];
    const float* lin2_w = (const float*)d_in[22];
    const float* lin2_b = (const float*)d_in[23];
    float* y = (float*)d_out;

    char* ws = (char*)d_ws;
    size_t off = 0;
    auto alloc = [&](size_t bytes) {
        void* p = ws + off;
        off = (off + bytes + 255) & ~(size_t)255;
        return p;
    };
    float* h = (float*)alloc((size_t)NN * D * 4);
    float* agg = (float*)alloc((size_t)NN * D * 4);
    float* invdeg = (float*)alloc((size_t)NN * 4);
    int* start = (int*)alloc((size_t)(NG + 1) * 4);
    float* qstar = (float*)alloc((size_t)NG * 128 * 4);   // 1 MB; ALIASED as w2r during MP phase
    float* hh = (float*)alloc((size_t)NG * 64 * 4);
    float* ccv = (float*)alloc((size_t)NG * 64 * 4);
    float* gruT_ih = (float*)alloc(192 * 64 * 4);
    float* gruT_hh = (float*)alloc(192 * 64 * 4);
    float* s2sT_ih = (float*)alloc(256 * 128 * 4);
    float* s2sT_hh = (float*)alloc(256 * 64 * 4);
    // w2r (bf16 nn_w2, 1 MB) aliases qstar (1 MB): w2r read only during MP; qstar used only after.
    __hip_bfloat16* w2r = (__hip_bfloat16*)qstar;

    // prep
    hipMemsetAsync(invdeg, 0, (size_t)NN * 4, stream);
    transpose_kernel<<<(192 * 64 + 255) / 256, 256, 0, stream>>>(gru_w_ih, gruT_ih, 192, 64);
    transpose_kernel<<<(192 * 64 + 255) / 256, 256, 0, stream>>>(gru_w_hh, gruT_hh, 192, 64);
    transpose_kernel<<<(256 * 128 + 255) / 256, 256, 0, stream>>>(s2s_w_ih, s2sT_ih, 256, 128);
    transpose_kernel<<<(256 * 64 + 255) / 256, 256, 0, stream>>>(s2s_w_hh, s2sT_hh, 256, 64);
    cvt_bf16_kernel<<<(64 * 8192 + 255) / 256, 256, 0, stream>>>(nn_w2, w2r, 64 * 8192);
    lin0_kernel<<<NN / 4, 256, 0, stream>>>(x, lin0_w, lin0_b, h);
    deg_kernel<<<(NE + 255) / 256, 256, 0, stream>>>(edge_index, invdeg);
    invdeg_kernel<<<(NN + 255) / 256, 256, 0, stream>>>(invdeg);
    starts_kernel<<<(NN + 255) / 256, 256, 0, stream>>>(batch, start);

    // 3 message-passing + conv+GRU iterations
    for (int it = 0; it < 3; it++) {
        hipMemsetAsync(agg, 0, (size_t)NN * D * 4, stream);
        msg_mfma_kernel<<<(NE + EB - 1) / EB, 256, 0, stream>>>(
            h, edge_attr, nn_w1, nn_b1, w2r, nn_b2, edge_index, agg);
        conv_gru_kernel<<<NN / 16, 256, 0, stream>>>(
            h, agg, invdeg, conv_root, conv_bias, gruT_ih, gruT_hh, gru_b_ih, gru_b_hh);
    }

    // Set2Set (qstar region no longer needed as w2r)
    hipMemsetAsync(qstar, 0, (size_t)NG * 128 * 4, stream);
    hipMemsetAsync(hh, 0, (size_t)NG * 64 * 4, stream);
    hipMemsetAsync(ccv, 0, (size_t)NG * 64 * 4, stream);
    for (int t = 0; t < 3; t++) {
        s2s_lstm_kernel<<<NG, 256, 0, stream>>>(qstar, hh, ccv, s2sT_ih, s2sT_hh, s2s_b_ih, s2s_b_hh);
        s2s_attn_kernel<<<NG, 64, 0, stream>>>(h, hh, start, qstar);
    }
    final_kernel<<<NG, 64, 0, stream>>>(qstar, lin1_w, lin1_b, lin2_w, lin2_b, y);
}

// Round 5
// 918.060 us; speedup vs baseline: 10.5117x; 1.0103x over previous
//
#include <hip/hip_runtime.h>
#include <hip/hip_bf16.h>

#define NN 50000    // nodes
#define NE 100000   // edges
#define NG 2048     // graphs
#define NF 14
#define D 64
#define EB 128      // edges per block in msg kernel (8 row-tiles, one per wave... rt=8 per wave, ct split)

typedef __attribute__((ext_vector_type(8))) short bf16x8;
typedef __attribute__((ext_vector_type(4))) float f32x4;

__device__ __forceinline__ float sigmoidf(float x) { return 1.f / (1.f + expf(-x)); }

// ---------------- utility ----------------
__global__ void cvt_bf16_kernel(const float* __restrict__ src, __hip_bfloat16* __restrict__ dst, int n) {
    int i = blockIdx.x * 256 + threadIdx.x;
    if (i < n) dst[i] = __float2bfloat16(src[i]);
}

// dst[c*rows + r] = src[r*cols + c]
__global__ void transpose_kernel(const float* __restrict__ src, float* __restrict__ dst,
                                 int rows, int cols) {
    int idx = blockIdx.x * 256 + threadIdx.x;
    if (idx < rows * cols) {
        int r = idx / cols, c = idx - r * cols;
        dst[c * rows + r] = src[idx];
    }
}

// ---------------- lin0: out = relu(x @ lin0_w.T + b) ----------------
__global__ void lin0_kernel(const float* __restrict__ x, const float* __restrict__ w,
                            const float* __restrict__ b, float* __restrict__ out) {
    int grp = threadIdx.x >> 6;
    int d = threadIdx.x & 63;
    int n = blockIdx.x * 4 + grp;
    __shared__ float xs[4][NF];
    int t = threadIdx.x;
    if (t < 4 * NF) {
        int r = t / NF, c = t - r * NF;
        int nn2 = blockIdx.x * 4 + r;
        xs[r][c] = (nn2 < NN) ? x[nn2 * NF + c] : 0.f;
    }
    __syncthreads();
    if (n >= NN) return;
    float acc = b[d];
#pragma unroll
    for (int k = 0; k < NF; k++) acc += xs[grp][k] * w[d * NF + k];
    out[n * D + d] = fmaxf(acc, 0.f);
}

// ================= MFMA fused message kernel =================
// Wave w of 4 owns o-columns [w*16, w*16+16); all 8 row-tiles (128 edges) per wave.
// Per i: S[rt] = hid_tile(rt) @ W2slice_i(ct=w) via 4 chained MFMA; acc[rt] += h[src,i] * S[rt].
__global__ __launch_bounds__(256, 2) void msg_mfma_kernel(
    const float* __restrict__ h, const float* __restrict__ ea,
    const float* __restrict__ w1, const float* __restrict__ b1,
    const __hip_bfloat16* __restrict__ w2r,  // bf16 nn_w2 [4096][128] row-major
    const float* __restrict__ b2, const int* __restrict__ ei,
    float* __restrict__ agg)
{
    // pool: hid[128][136] bf16 (preamble) aliases Bs[2][64][136] bf16 (main loop)
    // and B2s[64][72] bf16 (b2 pass, fits in Bs[0] half)
    __shared__ __align__(16) char upool[34816];
    __hip_bfloat16 (*hid)[136] = (__hip_bfloat16(*)[136])upool;
    __hip_bfloat16 (*Bs)[64][136] = (__hip_bfloat16(*)[64][136])upool;
    __hip_bfloat16 (*B2s)[72] = (__hip_bfloat16(*)[72])upool;
    __shared__ __align__(16) float hsrcT[64][128];  // hsrcT[i][e] = h[src_e][i], f32
    __shared__ float eas[EB][4];
    __shared__ float w1s[128][4];
    __shared__ float b1s[128];
    __shared__ int didx[EB];

    int tid = threadIdx.x;
    int e0 = blockIdx.x * EB;

    // --- stage ea, w1, b1, didx ---
    for (int idx = tid; idx < EB * 4; idx += 256) {
        int e = idx >> 2, j = idx & 3;
        int ge = e0 + e;
        eas[e][j] = (ge < NE) ? ea[ge * 4 + j] : 0.f;
    }
    if (tid < 128) {
        w1s[tid][0] = w1[tid * 4 + 0]; w1s[tid][1] = w1[tid * 4 + 1];
        w1s[tid][2] = w1[tid * 4 + 2]; w1s[tid][3] = w1[tid * 4 + 3];
        b1s[tid] = b1[tid];
    }
    if (tid < EB) didx[tid] = (e0 + tid < NE) ? ei[NE + e0 + tid] : -1;
    // --- gather h[src] -> hsrcT (transposed, f32); thread covers half a row ---
    {
        int e = tid >> 1, half = (tid & 1) * 32;
        int ge = e0 + e;
        int src = (ge < NE) ? ei[ge] : 0;
        const float4* hp = (const float4*)(h + (size_t)src * 64 + half);
#pragma unroll
        for (int u = 0; u < 8; u++) {
            float4 v = (ge < NE) ? hp[u] : make_float4(0.f, 0.f, 0.f, 0.f);
            hsrcT[half + u * 4 + 0][e] = v.x;
            hsrcT[half + u * 4 + 1][e] = v.y;
            hsrcT[half + u * 4 + 2][e] = v.z;
            hsrcT[half + u * 4 + 3][e] = v.w;
        }
    }
    __syncthreads();  // eas/w1s/b1s ready
    // --- hid[e][k] = relu(b1[k] + ea[e]·w1[k]) bf16 ---
    {
        int e = tid & 127, kb = (tid >> 7) * 64;
        float a0 = eas[e][0], a1 = eas[e][1], a2 = eas[e][2], a3 = eas[e][3];
        for (int k = kb; k < kb + 64; k += 4) {
            union { __hip_bfloat16 b[4]; uint2 uu; } pk;
#pragma unroll
            for (int u = 0; u < 4; u++) {
                float v = b1s[k + u] + a0 * w1s[k + u][0] + a1 * w1s[k + u][1] +
                          a2 * w1s[k + u][2] + a3 * w1s[k + u][3];
                pk.b[u] = __float2bfloat16(fmaxf(v, 0.f));
            }
            *(uint2*)&hid[e][k] = pk.uu;
        }
    }
    __syncthreads();  // hid ready

    int lane = tid & 63;
    int wid = tid >> 6;          // wave id = ct (o-column tile)
    int n = lane & 15, q = lane >> 4;
    int ocol = wid * 16 + n;

    // A-fragments (i-invariant): all 8 row-tiles, 4 k-steps
    bf16x8 afr[8][4];
#pragma unroll
    for (int rt = 0; rt < 8; rt++)
#pragma unroll
        for (int ks = 0; ks < 4; ks++)
            afr[rt][ks] = *(const bf16x8*)&hid[rt * 16 + n][ks * 32 + q * 8];
    __syncthreads();  // hid dead; pool becomes Bs

    // stage Bs[0] (slice i=0)
    int srow = tid >> 2, sseg = (tid & 3) * 32;
    {
        const bf16x8* gp = (const bf16x8*)(w2r + (size_t)srow * 128 + sseg);
        bf16x8* lp = (bf16x8*)&Bs[0][srow][sseg];
#pragma unroll
        for (int u = 0; u < 4; u++) lp[u] = gp[u];
    }
    __syncthreads();  // Bs[0] ready

    f32x4 acc[8];
#pragma unroll
    for (int rt = 0; rt < 8; rt++) acc[rt] = (f32x4){0.f, 0.f, 0.f, 0.f};

    for (int i = 0; i < 64; i++) {
        const int cur = i & 1;
        // early global load of next slice into registers
        bf16x8 pre[4];
        if (i + 1 < 64) {
            const bf16x8* gp = (const bf16x8*)(w2r + (size_t)(i + 1) * 8192 + srow * 128 + sseg);
#pragma unroll
            for (int u = 0; u < 4; u++) pre[u] = gp[u];
        }
        // B-frags for this wave's ct only
        bf16x8 bfr[4];
#pragma unroll
        for (int ks = 0; ks < 4; ks++)
            bfr[ks] = *(const bf16x8*)&Bs[cur][ocol][ks * 32 + q * 8];
        // per row-tile: chained MFMA over k, then f32 fixup with h[src, i]
#pragma unroll
        for (int rt = 0; rt < 8; rt++) {
            f32x4 S = (f32x4){0.f, 0.f, 0.f, 0.f};
#pragma unroll
            for (int ks = 0; ks < 4; ks++)
                S = __builtin_amdgcn_mfma_f32_16x16x32_bf16(afr[rt][ks], bfr[ks], S, 0, 0, 0);
            f32x4 hm = *(const f32x4*)&hsrcT[i][rt * 16 + q * 4];
#pragma unroll
            for (int r = 0; r < 4; r++) acc[rt][r] += hm[r] * S[r];
        }
        // late LDS store of next slice
        if (i + 1 < 64) {
            bf16x8* lp = (bf16x8*)&Bs[cur ^ 1][srow][sseg];
#pragma unroll
            for (int u = 0; u < 4; u++) lp[u] = pre[u];
        }
        __syncthreads();
    }

    // ---- b2 pass: acc[e,o] += sum_i h[src_e,i] * b2[i*64+o] via MFMA ----
    // stage B2s[o][i] into Bs[0] region (free now)
    for (int g = tid; g < 4096; g += 256) {
        B2s[g & 63][g >> 6] = __float2bfloat16(b2[g]);
    }
    __syncthreads();
    {
#pragma unroll
        for (int rt = 0; rt < 8; rt++) {
            f32x4 S2 = (f32x4){0.f, 0.f, 0.f, 0.f};
#pragma unroll
            for (int ks2 = 0; ks2 < 2; ks2++) {
                // A-frag: h[src_e, i] from hsrcT (scalar reads, once)
                union { __hip_bfloat16 b[8]; bf16x8 v; } pk;
#pragma unroll
                for (int j = 0; j < 8; j++)
                    pk.b[j] = __float2bfloat16(hsrcT[ks2 * 32 + q * 8 + j][rt * 16 + n]);
                bf16x8 bfr2 = *(const bf16x8*)&B2s[ocol][ks2 * 32 + q * 8];
                S2 = __builtin_amdgcn_mfma_f32_16x16x32_bf16(pk.v, bfr2, S2, 0, 0, 0);
            }
#pragma unroll
            for (int r = 0; r < 4; r++) acc[rt][r] += S2[r];
        }
    }

    // scatter: C layout col=lane&15 -> o, row=q*4+r -> edge within row-tile
#pragma unroll
    for (int rt = 0; rt < 8; rt++)
#pragma unroll
        for (int r = 0; r < 4; r++) {
            int e = rt * 16 + q * 4 + r;
            if (e0 + e < NE) {
                int dn = didx[e];
                atomicAdd(&agg[(size_t)dn * 64 + ocol], acc[rt][r]);
            }
        }
}

// ---------------- degree ----------------
__global__ void deg_kernel(const int* __restrict__ ei, float* __restrict__ deg) {
    int e = blockIdx.x * 256 + threadIdx.x;
    if (e < NE) atomicAdd(&deg[ei[NE + e]], 1.0f);
}
__global__ void invdeg_kernel(float* deg) {
    int n = blockIdx.x * 256 + threadIdx.x;
    if (n < NN) deg[n] = 1.0f / fmaxf(deg[n], 1.0f);
}

// ---------------- fused conv + GRU: h = GRUCell(relu(h@root + agg*invdeg + cbias), h) ----------------
__global__ __launch_bounds__(256) void conv_gru_kernel(
    float* __restrict__ h, const float* __restrict__ agg, const float* __restrict__ invdeg,
    const float* __restrict__ root, const float* __restrict__ cbias,
    const float* __restrict__ wihT, const float* __restrict__ whhT,
    const float* __restrict__ bih, const float* __restrict__ bhh)
{
    int tid = threadIdx.x;
    int grp = tid >> 6;
    int j = tid & 63;
    int n0 = blockIdx.x * 16;
    int nd0 = grp * 4;
    __shared__ float hs[16][64];
    __shared__ float ms[16][68];
    for (int i = tid; i < 1024; i += 256) {
        int nd = i >> 6, dd = i & 63;
        hs[nd][dd] = h[(n0 + nd) * D + dd];
    }
    __syncthreads();
    float mm[4] = {};
#pragma unroll 8
    for (int k = 0; k < 64; k++) {
        float rv = root[k * 64 + j];
#pragma unroll
        for (int q = 0; q < 4; q++) mm[q] += hs[nd0 + q][k] * rv;
    }
    float cb = cbias[j];
#pragma unroll
    for (int q = 0; q < 4; q++) {
        int nn2 = n0 + nd0 + q;
        float v = mm[q] + agg[(size_t)nn2 * 64 + j] * invdeg[nn2] + cb;
        ms[nd0 + q][j] = fmaxf(v, 0.f);
    }
    __syncthreads();
    float air[4] = {}, aiz[4] = {}, ain[4] = {};
    float ahr[4] = {}, ahz[4] = {}, ahn[4] = {};
#pragma unroll 4
    for (int k = 0; k < 64; k++) {
        float wr = wihT[k * 192 + j];
        float wz = wihT[k * 192 + 64 + j];
        float wn = wihT[k * 192 + 128 + j];
        float vr = whhT[k * 192 + j];
        float vz = whhT[k * 192 + 64 + j];
        float vn = whhT[k * 192 + 128 + j];
#pragma unroll
        for (int q = 0; q < 4; q++) {
            float mv = ms[nd0 + q][k], hv = hs[nd0 + q][k];
            air[q] = fmaf(mv, wr, air[q]);
            aiz[q] = fmaf(mv, wz, aiz[q]);
            ain[q] = fmaf(mv, wn, ain[q]);
            ahr[q] = fmaf(hv, vr, ahr[q]);
            ahz[q] = fmaf(hv, vz, ahz[q]);
            ahn[q] = fmaf(hv, vn, ahn[q]);
        }
    }
    float br = bih[j], bz = bih[64 + j], bn = bih[128 + j];
    float cr = bhh[j], cz = bhh[64 + j], cn = bhh[128 + j];
#pragma unroll
    for (int q = 0; q < 4; q++) {
        float r = sigmoidf(air[q] + br + ahr[q] + cr);
        float z = sigmoidf(aiz[q] + bz + ahz[q] + cz);
        float nn2 = tanhf(ain[q] + bn + r * (ahn[q] + cn));
        float hv = hs[nd0 + q][j];
        h[(n0 + nd0 + q) * D + j] = (1.f - z) * nn2 + z * hv;
    }
}

// ---------------- graph starts (batch sorted) ----------------
__global__ void starts_kernel(const int* __restrict__ batch, int* __restrict__ start) {
    int n = blockIdx.x * 256 + threadIdx.x;
    if (n >= NN) return;
    int b = batch[n];
    int bp = (n == 0) ? -1 : batch[n - 1];
    for (int g = bp + 1; g <= b; g++) start[g] = n;
    if (n == NN - 1) {
        for (int g = b + 1; g <= NG; g++) start[g] = NN;
    }
}

// ---------------- Set2Set LSTM step ----------------
__global__ void s2s_lstm_kernel(const float* __restrict__ qstar, float* __restrict__ hh,
                                float* __restrict__ cc, const float* __restrict__ wihT,
                                const float* __restrict__ whhT, const float* __restrict__ bih,
                                const float* __restrict__ bhh) {
    int g = blockIdx.x;
    int j = threadIdx.x;  // 256
    __shared__ float q[128], hsh[64], gates[256];
    if (j < 128) q[j] = qstar[g * 128 + j];
    if (j < 64) hsh[j] = hh[g * 64 + j];
    __syncthreads();
    float acc = bih[j] + bhh[j];
#pragma unroll 8
    for (int k = 0; k < 128; k++) acc = fmaf(q[k], wihT[k * 256 + j], acc);
#pragma unroll 8
    for (int k = 0; k < 64; k++) acc = fmaf(hsh[k], whhT[k * 256 + j], acc);
    gates[j] = acc;
    __syncthreads();
    if (j < 64) {
        float gi = gates[j], gf = gates[64 + j], gg = gates[128 + j], go = gates[192 + j];
        float c2 = sigmoidf(gf) * cc[g * 64 + j] + sigmoidf(gi) * tanhf(gg);
        float h2 = sigmoidf(go) * tanhf(c2);
        cc[g * 64 + j] = c2;
        hh[g * 64 + j] = h2;
    }
}

// ---------------- Set2Set attention + pooling; writes q_star ----------------
__global__ void s2s_attn_kernel(const float* __restrict__ out, const float* __restrict__ hh,
                                const int* __restrict__ start, float* __restrict__ qstar) {
    int g = blockIdx.x;
    int d = threadIdx.x;  // 64
    int n0 = start[g], n1 = start[g + 1];
    float hd = hh[g * 64 + d];
    float mx = -INFINITY;
    for (int n = n0; n < n1; n++) {
        float p = out[n * D + d] * hd;
#pragma unroll
        for (int off = 32; off; off >>= 1) p += __shfl_xor(p, off);
        mx = fmaxf(mx, p);
    }
    float sexp = 0.f, racc = 0.f;
    for (int n = n0; n < n1; n++) {
        float ond = out[n * D + d];
        float p = ond * hd;
#pragma unroll
        for (int off = 32; off; off >>= 1) p += __shfl_xor(p, off);
        float a = expf(p - mx);
        sexp += a;
        racc = fmaf(a, ond, racc);
    }
    float r = racc / (sexp + 1e-16f);
    qstar[g * 128 + d] = hd;
    qstar[g * 128 + 64 + d] = r;
}

// ---------------- head ----------------
__global__ void final_kernel(const float* __restrict__ qstar, const float* __restrict__ w1,
                             const float* __restrict__ b1, const float* __restrict__ w2,
                             const float* __restrict__ b2, float* __restrict__ y) {
    int g = blockIdx.x;
    int d = threadIdx.x;  // 64
    __shared__ float q[128];
    q[d] = qstar[g * 128 + d];
    q[64 + d] = qstar[g * 128 + 64 + d];
    __syncthreads();
    float acc = b1[d];
#pragma unroll 8
    for (int k = 0; k < 128; k++) acc = fmaf(q[k], w1[d * 128 + k], acc);
    acc = fmaxf(acc, 0.f);
    float p = acc * w2[d];
#pragma unroll
    for (int off = 32; off; off >>= 1) p += __shfl_xor(p, off);
    if (d == 0) y[g] = p + b2[0];
}

extern "C" void kernel_launch(void* const* d_in, const int* in_sizes, int n_in,
                              void* d_out, int out_size, void* d_ws, size_t ws_size,
                              hipStream_t stream) {
    (void)in_sizes; (void)n_in; (void)out_size; (void)ws_size;
    const float* x = (const float*)d_in[0];
    const int* edge_index = (const int*)d_in[1];
    const float* edge_attr = (const float*)d_in[2];
    const int* batch = (const int*)d_in[3];
    const float* lin0_w = (const float*)d_in[4];
    const float* lin0_b = (const float*)d_in[5];
    const float* nn_w1 = (const float*)d_in[6];
    const float* nn_b1 = (const float*)d_in[7];
    const float* nn_w2 = (const float*)d_in[8];
    const float* nn_b2 = (const float*)d_in[9];
    const float* conv_root = (const float*)d_in[10];
    const float* conv_bias = (const float*)d_in[11];
    const float* gru_w_ih = (const float*)d_in[12];
    const float* gru_w_hh = (const float*)d_in[13];
    const float* gru_b_ih = (const float*)d_in[14];
    const float* gru_b_hh = (const float*)d_in[15];
    const float* s2s_w_ih = (const float*)d_in[16];
    const float* s2s_w_hh = (const float*)d_in[17];
    const float* s2s_b_ih = (const float*)d_in[18];
    const float* s2s_b_hh = (const float*)d_in[19];
    const float* lin1_w = (const float*)d_in[20];
    const float* lin1_b = (const float*)d_in[21];
    const float* lin2_w = (const float*)d_in[22];
    const float* lin2_b = (const float*)d_in[23];
    float* y = (float*)d_out;

    char* ws = (char*)d_ws;
    size_t off = 0;
    auto alloc = [&](size_t bytes) {
        void* p = ws + off;
        off = (off + bytes + 255) & ~(size_t)255;
        return p;
    };
    float* h = (float*)alloc((size_t)NN * D * 4);
    float* agg = (float*)alloc((size_t)NN * D * 4);
    float* invdeg = (float*)alloc((size_t)NN * 4);
    int* start = (int*)alloc((size_t)(NG + 1) * 4);
    float* qstar = (float*)alloc((size_t)NG * 128 * 4);   // 1 MB; ALIASED as w2r during MP phase
    float* hh = (float*)alloc((size_t)NG * 64 * 4);
    float* ccv = (float*)alloc((size_t)NG * 64 * 4);
    float* gruT_ih = (float*)alloc(192 * 64 * 4);
    float* gruT_hh = (float*)alloc(192 * 64 * 4);
    float* s2sT_ih = (float*)alloc(256 * 128 * 4);
    float* s2sT_hh = (float*)alloc(256 * 64 * 4);
    __hip_bfloat16* w2r = (__hip_bfloat16*)qstar;

    // prep
    hipMemsetAsync(invdeg, 0, (size_t)NN * 4, stream);
    transpose_kernel<<<(192 * 64 + 255) / 256, 256, 0, stream>>>(gru_w_ih, gruT_ih, 192, 64);
    transpose_kernel<<<(192 * 64 + 255) / 256, 256, 0, stream>>>(gru_w_hh, gruT_hh, 192, 64);
    transpose_kernel<<<(256 * 128 + 255) / 256, 256, 0, stream>>>(s2s_w_ih, s2sT_ih, 256, 128);
    transpose_kernel<<<(256 * 64 + 255) / 256, 256, 0, stream>>>(s2s_w_hh, s2sT_hh, 256, 64);
    cvt_bf16_kernel<<<(64 * 8192 + 255) / 256, 256, 0, stream>>>(nn_w2, w2r, 64 * 8192);
    lin0_kernel<<<NN / 4, 256, 0, stream>>>(x, lin0_w, lin0_b, h);
    deg_kernel<<<(NE + 255) / 256, 256, 0, stream>>>(edge_index, invdeg);
    invdeg_kernel<<<(NN + 255) / 256, 256, 0, stream>>>(invdeg);
    starts_kernel<<<(NN + 255) / 256, 256, 0, stream>>>(batch, start);

    // 3 message-passing + conv+GRU iterations
    for (int it = 0; it < 3; it++) {
        hipMemsetAsync(agg, 0, (size_t)NN * D * 4, stream);
        msg_mfma_kernel<<<(NE + EB - 1) / EB, 256, 0, stream>>>(
            h, edge_attr, nn_w1, nn_b1, w2r, nn_b2, edge_index, agg);
        conv_gru_kernel<<<NN / 16, 256, 0, stream>>>(
            h, agg, invdeg, conv_root, conv_bias, gruT_ih, gruT_hh, gru_b_ih, gru_b_hh);
    }

    // Set2Set (qstar region no longer needed as w2r)
    hipMemsetAsync(qstar, 0, (size_t)NG * 128 * 4, stream);
    hipMemsetAsync(hh, 0, (size_t)NG * 64 * 4, stream);
    hipMemsetAsync(ccv, 0, (size_t)NG * 64 * 4, stream);
    for (int t = 0; t < 3; t++) {
        s2s_lstm_kernel<<<NG, 256, 0, stream>>>(qstar, hh, ccv, s2sT_ih, s2sT_hh, s2s_b_ih, s2s_b_hh);
        s2s_attn_kernel<<<NG, 64, 0, stream>>>(h, hh, start, qstar);
    }
    final_kernel<<<NG, 64, 0, stream>>>(qstar, lin1_w, lin1_b, lin2_w, lin2_b, y);
}

// Round 6
// 811.672 us; speedup vs baseline: 11.8896x; 1.1311x over previous
//
#include <hip/hip_runtime.h>
#include <hip/hip_bf16.h>

#define NN 50000    // nodes
#define NE 100000   // edges
#define NG 2048     // graphs
#define NF 14
#define D 64
#define EB 128      // edges per block in msg kernel

typedef __attribute__((ext_vector_type(8))) short bf16x8;
typedef __attribute__((ext_vector_type(4))) float f32x4;

__device__ __forceinline__ float sigmoidf(float x) { return 1.f / (1.f + expf(-x)); }

// ---------------- utility ----------------
__global__ void cvt_bf16_kernel(const float* __restrict__ src, __hip_bfloat16* __restrict__ dst, int n) {
    int i = blockIdx.x * 256 + threadIdx.x;
    if (i < n) dst[i] = __float2bfloat16(src[i]);
}

// dst[c*rows + r] = src[r*cols + c]
__global__ void transpose_kernel(const float* __restrict__ src, float* __restrict__ dst,
                                 int rows, int cols) {
    int idx = blockIdx.x * 256 + threadIdx.x;
    if (idx < rows * cols) {
        int r = idx / cols, c = idx - r * cols;
        dst[c * rows + r] = src[idx];
    }
}

// ---------------- lin0: out = relu(x @ lin0_w.T + b) ----------------
__global__ void lin0_kernel(const float* __restrict__ x, const float* __restrict__ w,
                            const float* __restrict__ b, float* __restrict__ out) {
    int grp = threadIdx.x >> 6;
    int d = threadIdx.x & 63;
    int n = blockIdx.x * 4 + grp;
    __shared__ float xs[4][NF];
    int t = threadIdx.x;
    if (t < 4 * NF) {
        int r = t / NF, c = t - r * NF;
        int nn2 = blockIdx.x * 4 + r;
        xs[r][c] = (nn2 < NN) ? x[nn2 * NF + c] : 0.f;
    }
    __syncthreads();
    if (n >= NN) return;
    float acc = b[d];
#pragma unroll
    for (int k = 0; k < NF; k++) acc += xs[grp][k] * w[d * NF + k];
    out[n * D + d] = fmaxf(acc, 0.f);
}

// ================= MFMA fused message kernel =================
// 512 threads = 8 waves. Wave wid = (half, ct): half = wid>>2 selects edge rows
// [half*64, half*64+64); ct = wid&3 selects o-cols [ct*16, ct*16+16).
// Each wave: 4 row-tiles, afr i-invariant in regs (64 VGPR).
// Per i: S[rt] = hid_tile @ W2slice_i(ct) (ks-outer: independent MFMAs);
// acc[rt] += h[src,i] * S[rt].
__global__ __launch_bounds__(512, 4) void msg_mfma_kernel(
    const float* __restrict__ h, const float* __restrict__ ea,
    const float* __restrict__ w1, const float* __restrict__ b1,
    const __hip_bfloat16* __restrict__ w2r,  // bf16 nn_w2 [4096][128] row-major
    const float* __restrict__ b2, const int* __restrict__ ei,
    float* __restrict__ agg)
{
    // pool: hid[128][136] bf16 (preamble) aliases Bs[2][64][136] bf16 (main loop)
    // and B2s[64][72] bf16 (b2 pass)
    __shared__ __align__(16) char upool[34816];
    __hip_bfloat16 (*hid)[136] = (__hip_bfloat16(*)[136])upool;
    __hip_bfloat16 (*Bs)[64][136] = (__hip_bfloat16(*)[64][136])upool;
    __hip_bfloat16 (*B2s)[72] = (__hip_bfloat16(*)[72])upool;
    __shared__ __align__(16) float hsrcT[64][132];  // hsrcT[i][e] = h[src_e][i], f32
    __shared__ float w1s[128][4];
    __shared__ float b1s[128];
    __shared__ int didx[EB];

    int tid = threadIdx.x;
    int e0 = blockIdx.x * EB;

    // --- stage didx / w1s / b1s ---
    if (tid < 128) {
        didx[tid] = (e0 + tid < NE) ? ei[NE + e0 + tid] : -1;
    } else if (tid < 256) {
        int k = tid - 128;
        w1s[k][0] = w1[k * 4 + 0]; w1s[k][1] = w1[k * 4 + 1];
        w1s[k][2] = w1[k * 4 + 2]; w1s[k][3] = w1[k * 4 + 3];
        b1s[k] = b1[k];
    }
    // --- gather h[src] -> hsrcT (transposed f32); 4 threads per edge ---
    {
        int e = tid >> 2, seg = (tid & 3) * 16;
        int ge = e0 + e;
        int src = (ge < NE) ? ei[ge] : 0;
        const float4* hp = (const float4*)(h + (size_t)src * 64 + seg);
#pragma unroll
        for (int u = 0; u < 4; u++) {
            float4 v = (ge < NE) ? hp[u] : make_float4(0.f, 0.f, 0.f, 0.f);
            hsrcT[seg + u * 4 + 0][e] = v.x;
            hsrcT[seg + u * 4 + 1][e] = v.y;
            hsrcT[seg + u * 4 + 2][e] = v.z;
            hsrcT[seg + u * 4 + 3][e] = v.w;
        }
    }
    __syncthreads();  // w1s/b1s ready
    // --- hid[e][k] = relu(b1[k] + ea[e]·w1[k]) bf16; 4 threads per edge (32 k each) ---
    {
        int e = tid & 127, kb = (tid >> 7) * 32;
        int ge = e0 + e;
        float4 av = (ge < NE) ? *(const float4*)(ea + (size_t)ge * 4)
                              : make_float4(0.f, 0.f, 0.f, 0.f);
        for (int k = kb; k < kb + 32; k += 4) {
            union { __hip_bfloat16 b[4]; uint2 uu; } pk;
#pragma unroll
            for (int u = 0; u < 4; u++) {
                float v = b1s[k + u] + av.x * w1s[k + u][0] + av.y * w1s[k + u][1] +
                          av.z * w1s[k + u][2] + av.w * w1s[k + u][3];
                pk.b[u] = __float2bfloat16(fmaxf(v, 0.f));
            }
            *(uint2*)&hid[e][k] = pk.uu;
        }
    }
    __syncthreads();  // hid ready

    int lane = tid & 63;
    int wid = tid >> 6;          // 0..7
    int half = wid >> 2;         // edge half
    int ct = wid & 3;            // o-column tile
    int n = lane & 15, q = lane >> 4;
    int ocol = ct * 16 + n;

    // A-fragments (i-invariant): 4 row-tiles x 4 k-steps = 64 VGPRs
    bf16x8 afr[4][4];
#pragma unroll
    for (int rt = 0; rt < 4; rt++)
#pragma unroll
        for (int ks = 0; ks < 4; ks++)
            afr[rt][ks] = *(const bf16x8*)&hid[half * 64 + rt * 16 + n][ks * 32 + q * 8];
    __syncthreads();  // hid dead; pool becomes Bs

    // stage Bs[0] (slice i=0): 512 threads x 32 B
    int srow = tid >> 3, sseg = (tid & 7) * 16;
    {
        const bf16x8* gp = (const bf16x8*)(w2r + (size_t)srow * 128 + sseg);
        bf16x8* lp = (bf16x8*)&Bs[0][srow][sseg];
        lp[0] = gp[0]; lp[1] = gp[1];
    }
    __syncthreads();  // Bs[0] ready

    f32x4 acc[4];
#pragma unroll
    for (int rt = 0; rt < 4; rt++) acc[rt] = (f32x4){0.f, 0.f, 0.f, 0.f};

    for (int i = 0; i < 64; i++) {
        const int cur = i & 1;
        // early global load of next slice into registers
        bf16x8 pre0, pre1;
        if (i + 1 < 64) {
            const bf16x8* gp = (const bf16x8*)(w2r + (size_t)(i + 1) * 8192 + srow * 128 + sseg);
            pre0 = gp[0]; pre1 = gp[1];
        }
        // B-frags for this wave's ct
        bf16x8 bfr[4];
#pragma unroll
        for (int ks = 0; ks < 4; ks++)
            bfr[ks] = *(const bf16x8*)&Bs[cur][ocol][ks * 32 + q * 8];
        // ks-outer: adjacent MFMAs independent (4 accumulator chains)
        f32x4 S[4];
#pragma unroll
        for (int rt = 0; rt < 4; rt++) S[rt] = (f32x4){0.f, 0.f, 0.f, 0.f};
#pragma unroll
        for (int ks = 0; ks < 4; ks++)
#pragma unroll
            for (int rt = 0; rt < 4; rt++)
                S[rt] = __builtin_amdgcn_mfma_f32_16x16x32_bf16(afr[rt][ks], bfr[ks], S[rt], 0, 0, 0);
        // fixup: acc += h[src,i] * S  (broadcast f32x4 LDS reads)
#pragma unroll
        for (int rt = 0; rt < 4; rt++) {
            f32x4 hm = *(const f32x4*)&hsrcT[i][half * 64 + rt * 16 + q * 4];
#pragma unroll
            for (int r = 0; r < 4; r++) acc[rt][r] += hm[r] * S[rt][r];
        }
        // late LDS store of next slice
        if (i + 1 < 64) {
            bf16x8* lp = (bf16x8*)&Bs[cur ^ 1][srow][sseg];
            lp[0] = pre0; lp[1] = pre1;
        }
        __syncthreads();
    }

    // ---- b2 pass: acc[e,o] += sum_i h[src_e,i] * b2[i*64+o] via MFMA ----
    for (int g = tid; g < 4096; g += 512) {
        B2s[g & 63][g >> 6] = __float2bfloat16(b2[g]);
    }
    __syncthreads();
#pragma unroll
    for (int rt = 0; rt < 4; rt++) {
        f32x4 S2 = (f32x4){0.f, 0.f, 0.f, 0.f};
#pragma unroll
        for (int ks2 = 0; ks2 < 2; ks2++) {
            union { __hip_bfloat16 b[8]; bf16x8 v; } pk;
#pragma unroll
            for (int j = 0; j < 8; j++)
                pk.b[j] = __float2bfloat16(hsrcT[ks2 * 32 + q * 8 + j][half * 64 + rt * 16 + n]);
            bf16x8 bfr2 = *(const bf16x8*)&B2s[ocol][ks2 * 32 + q * 8];
            S2 = __builtin_amdgcn_mfma_f32_16x16x32_bf16(pk.v, bfr2, S2, 0, 0, 0);
        }
#pragma unroll
        for (int r = 0; r < 4; r++) acc[rt][r] += S2[r];
    }

    // scatter: C layout col=lane&15 -> o, row=q*4+r -> edge within row-tile
#pragma unroll
    for (int rt = 0; rt < 4; rt++)
#pragma unroll
        for (int r = 0; r < 4; r++) {
            int e = half * 64 + rt * 16 + q * 4 + r;
            if (e0 + e < NE) {
                int dn = didx[e];
                atomicAdd(&agg[(size_t)dn * 64 + ocol], acc[rt][r]);
            }
        }
}

// ---------------- degree ----------------
__global__ void deg_kernel(const int* __restrict__ ei, float* __restrict__ deg) {
    int e = blockIdx.x * 256 + threadIdx.x;
    if (e < NE) atomicAdd(&deg[ei[NE + e]], 1.0f);
}
__global__ void invdeg_kernel(float* deg) {
    int n = blockIdx.x * 256 + threadIdx.x;
    if (n < NN) deg[n] = 1.0f / fmaxf(deg[n], 1.0f);
}

// ---------------- fused conv + GRU ----------------
__global__ __launch_bounds__(256) void conv_gru_kernel(
    float* __restrict__ h, const float* __restrict__ agg, const float* __restrict__ invdeg,
    const float* __restrict__ root, const float* __restrict__ cbias,
    const float* __restrict__ wihT, const float* __restrict__ whhT,
    const float* __restrict__ bih, const float* __restrict__ bhh)
{
    int tid = threadIdx.x;
    int grp = tid >> 6;
    int j = tid & 63;
    int n0 = blockIdx.x * 16;
    int nd0 = grp * 4;
    __shared__ float hs[16][64];
    __shared__ float ms[16][68];
    for (int i = tid; i < 1024; i += 256) {
        int nd = i >> 6, dd = i & 63;
        hs[nd][dd] = h[(n0 + nd) * D + dd];
    }
    __syncthreads();
    float mm[4] = {};
#pragma unroll 8
    for (int k = 0; k < 64; k++) {
        float rv = root[k * 64 + j];
#pragma unroll
        for (int q = 0; q < 4; q++) mm[q] += hs[nd0 + q][k] * rv;
    }
    float cb = cbias[j];
#pragma unroll
    for (int q = 0; q < 4; q++) {
        int nn2 = n0 + nd0 + q;
        float v = mm[q] + agg[(size_t)nn2 * 64 + j] * invdeg[nn2] + cb;
        ms[nd0 + q][j] = fmaxf(v, 0.f);
    }
    __syncthreads();
    float air[4] = {}, aiz[4] = {}, ain[4] = {};
    float ahr[4] = {}, ahz[4] = {}, ahn[4] = {};
#pragma unroll 4
    for (int k = 0; k < 64; k++) {
        float wr = wihT[k * 192 + j];
        float wz = wihT[k * 192 + 64 + j];
        float wn = wihT[k * 192 + 128 + j];
        float vr = whhT[k * 192 + j];
        float vz = whhT[k * 192 + 64 + j];
        float vn = whhT[k * 192 + 128 + j];
#pragma unroll
        for (int q = 0; q < 4; q++) {
            float mv = ms[nd0 + q][k], hv = hs[nd0 + q][k];
            air[q] = fmaf(mv, wr, air[q]);
            aiz[q] = fmaf(mv, wz, aiz[q]);
            ain[q] = fmaf(mv, wn, ain[q]);
            ahr[q] = fmaf(hv, vr, ahr[q]);
            ahz[q] = fmaf(hv, vz, ahz[q]);
            ahn[q] = fmaf(hv, vn, ahn[q]);
        }
    }
    float br = bih[j], bz = bih[64 + j], bn = bih[128 + j];
    float cr = bhh[j], cz = bhh[64 + j], cn = bhh[128 + j];
#pragma unroll
    for (int q = 0; q < 4; q++) {
        float r = sigmoidf(air[q] + br + ahr[q] + cr);
        float z = sigmoidf(aiz[q] + bz + ahz[q] + cz);
        float nn2 = tanhf(ain[q] + bn + r * (ahn[q] + cn));
        float hv = hs[nd0 + q][j];
        h[(n0 + nd0 + q) * D + j] = (1.f - z) * nn2 + z * hv;
    }
}

// ---------------- graph starts (batch sorted) ----------------
__global__ void starts_kernel(const int* __restrict__ batch, int* __restrict__ start) {
    int n = blockIdx.x * 256 + threadIdx.x;
    if (n >= NN) return;
    int b = batch[n];
    int bp = (n == 0) ? -1 : batch[n - 1];
    for (int g = bp + 1; g <= b; g++) start[g] = n;
    if (n == NN - 1) {
        for (int g = b + 1; g <= NG; g++) start[g] = NN;
    }
}

// ---------------- Set2Set LSTM step ----------------
__global__ void s2s_lstm_kernel(const float* __restrict__ qstar, float* __restrict__ hh,
                                float* __restrict__ cc, const float* __restrict__ wihT,
                                const float* __restrict__ whhT, const float* __restrict__ bih,
                                const float* __restrict__ bhh) {
    int g = blockIdx.x;
    int j = threadIdx.x;  // 256
    __shared__ float q[128], hsh[64], gates[256];
    if (j < 128) q[j] = qstar[g * 128 + j];
    if (j < 64) hsh[j] = hh[g * 64 + j];
    __syncthreads();
    float acc = bih[j] + bhh[j];
#pragma unroll 8
    for (int k = 0; k < 128; k++) acc = fmaf(q[k], wihT[k * 256 + j], acc);
#pragma unroll 8
    for (int k = 0; k < 64; k++) acc = fmaf(hsh[k], whhT[k * 256 + j], acc);
    gates[j] = acc;
    __syncthreads();
    if (j < 64) {
        float gi = gates[j], gf = gates[64 + j], gg = gates[128 + j], go = gates[192 + j];
        float c2 = sigmoidf(gf) * cc[g * 64 + j] + sigmoidf(gi) * tanhf(gg);
        float h2 = sigmoidf(go) * tanhf(c2);
        cc[g * 64 + j] = c2;
        hh[g * 64 + j] = h2;
    }
}

// ---------------- Set2Set attention + pooling; 4 node-groups per block ----------------
__global__ void s2s_attn_kernel(const float* __restrict__ out, const float* __restrict__ hh,
                                const int* __restrict__ start, float* __restrict__ qstar) {
    int g = blockIdx.x;
    int tid = threadIdx.x;  // 256
    int d = tid & 63, sub = tid >> 6;
    int n0 = start[g], n1 = start[g + 1];
    float hd = hh[g * 64 + d];
    __shared__ float red[4][64];
    __shared__ float mxS[4], seS[4];
    float mx = -INFINITY;
    for (int n = n0 + sub; n < n1; n += 4) {
        float p = out[n * D + d] * hd;
#pragma unroll
        for (int off = 32; off; off >>= 1) p += __shfl_xor(p, off);
        mx = fmaxf(mx, p);
    }
    if (d == 0) mxS[sub] = mx;
    __syncthreads();
    mx = fmaxf(fmaxf(mxS[0], mxS[1]), fmaxf(mxS[2], mxS[3]));
    float sexp = 0.f, racc = 0.f;
    for (int n = n0 + sub; n < n1; n += 4) {
        float ond = out[n * D + d];
        float p = ond * hd;
#pragma unroll
        for (int off = 32; off; off >>= 1) p += __shfl_xor(p, off);
        float a = expf(p - mx);
        sexp += a;
        racc = fmaf(a, ond, racc);
    }
    red[sub][d] = racc;
    if (d == 0) seS[sub] = sexp;
    __syncthreads();
    if (sub == 0) {
        float rtot = red[0][d] + red[1][d] + red[2][d] + red[3][d];
        float stot = seS[0] + seS[1] + seS[2] + seS[3];
        float r = rtot / (stot + 1e-16f);
        qstar[g * 128 + d] = hd;
        qstar[g * 128 + 64 + d] = r;
    }
}

// ---------------- head ----------------
__global__ void final_kernel(const float* __restrict__ qstar, const float* __restrict__ w1,
                             const float* __restrict__ b1, const float* __restrict__ w2,
                             const float* __restrict__ b2, float* __restrict__ y) {
    int g = blockIdx.x;
    int d = threadIdx.x;  // 64
    __shared__ float q[128];
    q[d] = qstar[g * 128 + d];
    q[64 + d] = qstar[g * 128 + 64 + d];
    __syncthreads();
    float acc = b1[d];
#pragma unroll 8
    for (int k = 0; k < 128; k++) acc = fmaf(q[k], w1[d * 128 + k], acc);
    acc = fmaxf(acc, 0.f);
    float p = acc * w2[d];
#pragma unroll
    for (int off = 32; off; off >>= 1) p += __shfl_xor(p, off);
    if (d == 0) y[g] = p + b2[0];
}

extern "C" void kernel_launch(void* const* d_in, const int* in_sizes, int n_in,
                              void* d_out, int out_size, void* d_ws, size_t ws_size,
                              hipStream_t stream) {
    (void)in_sizes; (void)n_in; (void)out_size; (void)ws_size;
    const float* x = (const float*)d_in[0];
    const int* edge_index = (const int*)d_in[1];
    const float* edge_attr = (const float*)d_in[2];
    const int* batch = (const int*)d_in[3];
    const float* lin0_w = (const float*)d_in[4];
    const float* lin0_b = (const float*)d_in[5];
    const float* nn_w1 = (const float*)d_in[6];
    const float* nn_b1 = (const float*)d_in[7];
    const float* nn_w2 = (const float*)d_in[8];
    const float* nn_b2 = (const float*)d_in[9];
    const float* conv_root = (const float*)d_in[10];
    const float* conv_bias = (const float*)d_in[11];
    const float* gru_w_ih = (const float*)d_in[12];
    const float* gru_w_hh = (const float*)d_in[13];
    const float* gru_b_ih = (const float*)d_in[14];
    const float* gru_b_hh = (const float*)d_in[15];
    const float* s2s_w_ih = (const float*)d_in[16];
    const float* s2s_w_hh = (const float*)d_in[17];
    const float* s2s_b_ih = (const float*)d_in[18];
    const float* s2s_b_hh = (const float*)d_in[19];
    const float* lin1_w = (const float*)d_in[20];
    const float* lin1_b = (const float*)d_in[21];
    const float* lin2_w = (const float*)d_in[22];
    const float* lin2_b = (const float*)d_in[23];
    float* y = (float*)d_out;

    char* ws = (char*)d_ws;
    size_t off = 0;
    auto alloc = [&](size_t bytes) {
        void* p = ws + off;
        off = (off + bytes + 255) & ~(size_t)255;
        return p;
    };
    float* h = (float*)alloc((size_t)NN * D * 4);
    float* agg = (float*)alloc((size_t)NN * D * 4);
    float* invdeg = (float*)alloc((size_t)NN * 4);
    int* start = (int*)alloc((size_t)(NG + 1) * 4);
    float* qstar = (float*)alloc((size_t)NG * 128 * 4);   // 1 MB; ALIASED as w2r during MP phase
    float* hh = (float*)alloc((size_t)NG * 64 * 4);
    float* ccv = (float*)alloc((size_t)NG * 64 * 4);
    float* gruT_ih = (float*)alloc(192 * 64 * 4);
    float* gruT_hh = (float*)alloc(192 * 64 * 4);
    float* s2sT_ih = (float*)alloc(256 * 128 * 4);
    float* s2sT_hh = (float*)alloc(256 * 64 * 4);
    __hip_bfloat16* w2r = (__hip_bfloat16*)qstar;

    // prep
    hipMemsetAsync(invdeg, 0, (size_t)NN * 4, stream);
    transpose_kernel<<<(192 * 64 + 255) / 256, 256, 0, stream>>>(gru_w_ih, gruT_ih, 192, 64);
    transpose_kernel<<<(192 * 64 + 255) / 256, 256, 0, stream>>>(gru_w_hh, gruT_hh, 192, 64);
    transpose_kernel<<<(256 * 128 + 255) / 256, 256, 0, stream>>>(s2s_w_ih, s2sT_ih, 256, 128);
    transpose_kernel<<<(256 * 64 + 255) / 256, 256, 0, stream>>>(s2s_w_hh, s2sT_hh, 256, 64);
    cvt_bf16_kernel<<<(64 * 8192 + 255) / 256, 256, 0, stream>>>(nn_w2, w2r, 64 * 8192);
    lin0_kernel<<<NN / 4, 256, 0, stream>>>(x, lin0_w, lin0_b, h);
    deg_kernel<<<(NE + 255) / 256, 256, 0, stream>>>(edge_index, invdeg);
    invdeg_kernel<<<(NN + 255) / 256, 256, 0, stream>>>(invdeg);
    starts_kernel<<<(NN + 255) / 256, 256, 0, stream>>>(batch, start);

    // 3 message-passing + conv+GRU iterations
    for (int it = 0; it < 3; it++) {
        hipMemsetAsync(agg, 0, (size_t)NN * D * 4, stream);
        msg_mfma_kernel<<<(NE + EB - 1) / EB, 512, 0, stream>>>(
            h, edge_attr, nn_w1, nn_b1, w2r, nn_b2, edge_index, agg);
        conv_gru_kernel<<<NN / 16, 256, 0, stream>>>(
            h, agg, invdeg, conv_root, conv_bias, gruT_ih, gruT_hh, gru_b_ih, gru_b_hh);
    }

    // Set2Set (qstar region no longer needed as w2r)
    hipMemsetAsync(qstar, 0, (size_t)NG * 128 * 4, stream);
    hipMemsetAsync(hh, 0, (size_t)NG * 64 * 4, stream);
    hipMemsetAsync(ccv, 0, (size_t)NG * 64 * 4, stream);
    for (int t = 0; t < 3; t++) {
        s2s_lstm_kernel<<<NG, 256, 0, stream>>>(qstar, hh, ccv, s2sT_ih, s2sT_hh, s2s_b_ih, s2s_b_hh);
        s2s_attn_kernel<<<NG, 256, 0, stream>>>(h, hh, start, qstar);
    }
    final_kernel<<<NG, 64, 0, stream>>>(qstar, lin1_w, lin1_b, lin2_w, lin2_b, y);
}